// Round 1
// baseline (471.765 us; speedup 1.0000x reference)
//
#include <hip/hip_runtime.h>
#include <math.h>

// Problem constants (fixed by setup_inputs)
#define BB 4
#define SS 512
#define EE 512
#define NH 8
#define HD 64
#define NC 128

__device__ __forceinline__ float clampf(float v, float lo, float hi) {
  return fminf(fmaxf(v, lo), hi);
}

__device__ __forceinline__ float waveRedSum(float v) {
#pragma unroll
  for (int o = 32; o; o >>= 1) v += __shfl_xor(v, o);
  return v;
}
__device__ __forceinline__ float waveRedMax(float v) {
#pragma unroll
  for (int o = 32; o; o >>= 1) v = fmaxf(v, __shfl_xor(v, o));
  return v;
}
// blockDim.x == 256 (4 waves) assumed
__device__ __forceinline__ float blockRedSum(float v, float* red) {
  int tid = threadIdx.x;
  v = waveRedSum(v);
  __syncthreads();
  if ((tid & 63) == 0) red[tid >> 6] = v;
  __syncthreads();
  return red[0] + red[1] + red[2] + red[3];
}
__device__ __forceinline__ float blockRedMax(float v, float* red) {
  int tid = threadIdx.x;
  v = waveRedMax(v);
  __syncthreads();
  if ((tid & 63) == 0) red[tid >> 6] = v;
  __syncthreads();
  return fmaxf(fmaxf(red[0], red[1]), fmaxf(red[2], red[3]));
}

// ---------------------------------------------------------------------------
// K0: zero the accumulator block
__global__ void k_zero(float* acc) {
  if (threadIdx.x < 32) acc[threadIdx.x] = 0.0f;
}

// ---------------------------------------------------------------------------
// K1: fused QKV projection. x[2048,512] @ W[512,512] + b, stored permuted as
// [B,H,S,HD]. grid (N/64=8, M/64=32, 3), block 256.
__global__ __launch_bounds__(256) void k_qkv(
    const float* __restrict__ x,
    const float* __restrict__ Wq, const float* __restrict__ bq,
    const float* __restrict__ Wk, const float* __restrict__ bk,
    const float* __restrict__ Wv, const float* __restrict__ bv,
    float* __restrict__ q, float* __restrict__ k, float* __restrict__ v) {
  const int which = blockIdx.z;
  const float* W = (which == 0) ? Wq : (which == 1) ? Wk : Wv;
  const float* bias = (which == 0) ? bq : (which == 1) ? bk : bv;
  float* dst = (which == 0) ? q : (which == 1) ? k : v;
  const int n0 = blockIdx.x * 64, m0 = blockIdx.y * 64;
  __shared__ float As[64][33];
  __shared__ float Bs[32][65];
  const int tid = threadIdx.x;
  const int tx = tid & 15, ty = tid >> 4;
  float acc[4][4] = {};
  for (int k0 = 0; k0 < EE; k0 += 32) {
#pragma unroll
    for (int t = 0; t < 8; ++t) {
      int idx = tid + t * 256;
      int r = idx >> 5, c = idx & 31;
      As[r][c] = x[(m0 + r) * EE + k0 + c];
    }
#pragma unroll
    for (int t = 0; t < 8; ++t) {
      int idx = tid + t * 256;
      int kk = idx >> 6, n = idx & 63;
      Bs[kk][n] = W[(k0 + kk) * EE + n0 + n];
    }
    __syncthreads();
#pragma unroll
    for (int kk = 0; kk < 32; ++kk) {
      float a[4], b[4];
#pragma unroll
      for (int i = 0; i < 4; ++i) a[i] = As[ty + 16 * i][kk];
#pragma unroll
      for (int j = 0; j < 4; ++j) b[j] = Bs[kk][tx + 16 * j];
#pragma unroll
      for (int i = 0; i < 4; ++i)
#pragma unroll
        for (int j = 0; j < 4; ++j) acc[i][j] += a[i] * b[j];
    }
    __syncthreads();
  }
#pragma unroll
  for (int i = 0; i < 4; ++i) {
    int m = m0 + ty + 16 * i;        // global row = b*S + si
    int b_ = m >> 9, si = m & 511;
#pragma unroll
    for (int j = 0; j < 4; ++j) {
      int n = n0 + tx + 16 * j;      // = h*64 + d
      int h = n >> 6, d = n & 63;
      dst[(((size_t)(b_ * NH + h) * SS) + si) * HD + d] = acc[i][j] + bias[n];
    }
  }
}

// ---------------------------------------------------------------------------
// K2: scores s = clip(q.k^T * scale, -15, 15), per (b,h). grid (8,8,32).
__global__ __launch_bounds__(256) void k_scores(
    const float* __restrict__ q, const float* __restrict__ k,
    float* __restrict__ s) {
  const int bh = blockIdx.z;
  const int i0 = blockIdx.y * 64, j0 = blockIdx.x * 64;
  __shared__ float Qs[64][65], Ks[64][65];
  const float* qb = q + (size_t)bh * SS * HD;
  const float* kb = k + (size_t)bh * SS * HD;
  const int tid = threadIdx.x, tx = tid & 15, ty = tid >> 4;
#pragma unroll
  for (int t = 0; t < 16; ++t) {
    int idx = tid + t * 256;
    int r = idx >> 6, d = idx & 63;
    Qs[r][d] = qb[(size_t)(i0 + r) * HD + d];
    Ks[r][d] = kb[(size_t)(j0 + r) * HD + d];
  }
  __syncthreads();
  float acc[4][4] = {};
#pragma unroll
  for (int d = 0; d < 64; ++d) {
    float a[4], b[4];
#pragma unroll
    for (int i = 0; i < 4; ++i) a[i] = Qs[ty + 16 * i][d];
#pragma unroll
    for (int j = 0; j < 4; ++j) b[j] = Ks[tx + 16 * j][d];
#pragma unroll
    for (int i = 0; i < 4; ++i)
#pragma unroll
      for (int j = 0; j < 4; ++j) acc[i][j] += a[i] * b[j];
  }
  const float scale = 0.125f;  // hd^-0.5
  float* sb = s + (size_t)bh * SS * SS;
#pragma unroll
  for (int i = 0; i < 4; ++i)
#pragma unroll
    for (int j = 0; j < 4; ++j) {
      float val = acc[i][j] * scale;
      // nan_to_num(nan=0, posinf=10, neginf=-10) then clip(-15,15)
      if (isnan(val)) val = 0.0f;
      else if (isinf(val)) val = (val > 0.f) ? 10.0f : -10.0f;
      val = clampf(val, -15.0f, 15.0f);
      sb[(size_t)(i0 + ty + 16 * i) * SS + (j0 + tx + 16 * j)] = val;
    }
}

// ---------------------------------------------------------------------------
// K3: ma = mean over heads of s. float4 grid-stride. 262144 float4 elems.
__global__ __launch_bounds__(256) void k_ma(const float* __restrict__ s,
                                            float* __restrict__ ma) {
  int idx = blockIdx.x * 256 + threadIdx.x;  // 0..262143
  const int perB = SS * SS / 4;
  int b_ = idx / perB;
  int r = idx - b_ * perB;
  const float4* sp = (const float4*)s;
  float4 a = {0.f, 0.f, 0.f, 0.f};
#pragma unroll
  for (int h = 0; h < NH; ++h) {
    float4 t = sp[(size_t)(b_ * NH + h) * perB + r];
    a.x += t.x; a.y += t.y; a.z += t.z; a.w += t.w;
  }
  a.x *= 0.125f; a.y *= 0.125f; a.z *= 0.125f; a.w *= 0.125f;
  ((float4*)ma)[idx] = a;
}

// ---------------------------------------------------------------------------
// K4: autopoietic transform per row (b,i): softmax p, entropy, Fm, sigmoid
// path, t_un = sig*Fm; accumulate per-batch reductions. 2048 blocks x 256.
__global__ __launch_bounds__(256) void k_transform(
    const float* __restrict__ ma, const float* __restrict__ w1,
    const float* __restrict__ b1, const float* __restrict__ w2,
    const float* __restrict__ b2, float* __restrict__ t_un,
    float* __restrict__ acc) {
  const int row = blockIdx.x;        // b*S + i
  const int b_ = row >> 9;
  const int tid = threadIdx.x;
  __shared__ float red[4];
  __shared__ float w1s[NC], b1s[NC], w2s[NC];
  if (tid < NC) { w1s[tid] = w1[tid]; b1s[tid] = b1[tid]; w2s[tid] = w2[tid]; }
  const float* mrow = ma + (size_t)row * SS;
  float m0 = mrow[tid], m1 = mrow[tid + 256];

  // p = softmax(clip(ma,-10,10))
  float mc0 = clampf(m0, -10.f, 10.f), mc1 = clampf(m1, -10.f, 10.f);
  float mx = blockRedMax(fmaxf(mc0, mc1), red);
  float e0 = expf(mc0 - mx), e1 = expf(mc1 - mx);
  float esum = blockRedSum(e0 + e1, red);
  float inv = 1.0f / esum;
  float p0 = e0 * inv, p1 = e1 * inv;
  float H0 = -p0 * logf(p0 + 1e-6f), H1 = -p1 * logf(p1 + 1e-6f);

  // Fm = softmax(3*Hent)
  float mx2 = blockRedMax(fmaxf(3.f * H0, 3.f * H1), red);
  float f0 = expf(3.f * H0 - mx2), f1 = expf(3.f * H1 - mx2);
  float fsum = blockRedSum(f0 + f1, red);
  float finv = 1.0f / fsum;
  float F0 = f0 * finv, F1 = f1 * finv;

  // sigmoid(taylor(ap)) ; sa = clip(ma,-8,8)*0.05 (|sa|<=0.4, outer clip no-op)
  float sa0 = clampf(m0, -8.f, 8.f) * 0.05f;
  float sa1 = clampf(m1, -8.f, 8.f) * 0.05f;
  float ap0 = 0.f, ap1 = 0.f;
#pragma unroll 4
  for (int c = 0; c < NC; ++c) {
    float h0 = fminf(fmaxf(sa0 * w1s[c] + b1s[c], 0.f), 5.f);  // relu(clip(.,-5,5))
    float h1 = fminf(fmaxf(sa1 * w1s[c] + b1s[c], 0.f), 5.f);
    ap0 += h0 * w2s[c];
    ap1 += h1 * w2s[c];
  }
  float b2v = b2[0];
  ap0 = clampf(ap0 + b2v, -5.f, 5.f);
  ap1 = clampf(ap1 + b2v, -5.f, 5.f);
  float tay0 = clampf(1.0f + 0.05f * (ap0 * 50.0f), 0.5f, 1.5f);
  float tay1 = clampf(1.0f + 0.05f * (ap1 * 50.0f), 0.5f, 1.5f);
  float sig0 = 1.0f / (1.0f + expf(-tay0));
  float sig1 = 1.0f / (1.0f + expf(-tay1));
  float t0 = sig0 * F0, t1 = sig1 * F1;
  t_un[(size_t)row * SS + tid] = t0;
  t_un[(size_t)row * SS + tid + 256] = t1;

  // per-batch reductions (on raw ma and unscaled t)
  float sma = blockRedSum(m0 + m1, red);
  float sma2 = blockRedSum(m0 * m0 + m1 * m1, red);
  float mabs = blockRedMax(fmaxf(fabsf(m0), fabsf(m1)), red);
  float st = blockRedSum(t0 + t1, red);
  float st2 = blockRedSum(t0 * t0 + t1 * t1, red);
  float sH = blockRedSum(H0 + H1, red);
  if (tid == 0) {
    atomicAdd(&acc[b_ * 8 + 0], sma);
    atomicAdd(&acc[b_ * 8 + 1], sma2);
    atomicMax((unsigned int*)&acc[b_ * 8 + 2], __float_as_uint(mabs));
    atomicAdd(&acc[b_ * 8 + 3], st);
    atomicAdd(&acc[b_ * 8 + 4], st2);
    atomicAdd(&acc[b_ * 8 + 5], sH);
  }
}

// ---------------------------------------------------------------------------
// K5: fold per-batch scalars into blend constants c0,c1,c2.
__global__ void k_consts(const float* __restrict__ acc, float* __restrict__ cst) {
  int b_ = threadIdx.x;
  if (b_ >= BB) return;
  const float N = (float)(SS * SS);
  float sma = acc[b_ * 8 + 0], sma2 = acc[b_ * 8 + 1];
  float mabs = __uint_as_float(((const unsigned int*)acc)[b_ * 8 + 2]);
  float st = acc[b_ * 8 + 3], st2 = acc[b_ * 8 + 4], sH = acc[b_ * 8 + 5];
  float eo = sqrtf(sma2) + 1e-4f;
  float et = sqrtf(st2) + 1e-4f;
  float r = clampf(eo / et, 0.8f, 1.2f);
  float tmean = r * st / N;
  float om = sma / N;
  float vart = r * r * fmaxf(st2 / N - (st / N) * (st / N), 0.f);
  float tstd = sqrtf(fmaxf(vart, 0.01f));
  float varo = fmaxf(sma2 / N - om * om, 0.f);
  float ostd = sqrtf(fmaxf(varo, 0.01f));
  float gd = clampf(ostd / tstd, 0.8f, 1.2f);
  float ar = clampf(mabs, 1.f, 10.f);
  float sm = clampf(0.3f / log1pf(ar), 0.1f, 0.5f);
  float ent = sH / N;
  float ne = ent / logf((float)SS);
  float rr = 0.4f * (1.f - clampf(ne, 0.f, 0.4f));
  float G = sm * gd;
  cst[b_ * 4 + 0] = rr * (1.f - G) * tmean;  // c0
  cst[b_ * 4 + 1] = rr * G * r;              // c1 (multiplies t_un)
  cst[b_ * 4 + 2] = rr;                      // c2 (multiplies ma)
}

// ---------------------------------------------------------------------------
// K6: blend + row softmax, in-place s -> attn. grid (512, 32), block 256.
__global__ __launch_bounds__(256) void k_blend(
    float* __restrict__ s, const float* __restrict__ ma,
    const float* __restrict__ t_un, const float* __restrict__ cst,
    const float* __restrict__ tau) {
  const int i = blockIdx.x;
  const int bh = blockIdx.y;
  const int b_ = bh >> 3;
  const int tid = threadIdx.x;
  __shared__ float red[4];
  const float c0 = cst[b_ * 4 + 0], c1 = cst[b_ * 4 + 1], c2 = cst[b_ * 4 + 2];
  const float itau = 1.0f / tau[0];
  float* srow = s + ((size_t)bh * SS + i) * SS;
  const float* mrow = ma + ((size_t)b_ * SS + i) * SS;
  const float* trow = t_un + ((size_t)b_ * SS + i) * SS;
  float v0 = (srow[tid] + c0 + c1 * trow[tid] - c2 * mrow[tid]) * itau;
  float v1 = (srow[tid + 256] + c0 + c1 * trow[tid + 256] - c2 * mrow[tid + 256]) * itau;
  float mx = blockRedMax(fmaxf(v0, v1), red);
  float e0 = expf(v0 - mx), e1 = expf(v1 - mx);
  float sum = blockRedSum(e0 + e1, red);
  float inv = 1.0f / sum;
  srow[tid] = e0 * inv;
  srow[tid + 256] = e1 * inv;
}

// ---------------------------------------------------------------------------
// K7: out = attn @ v per (b,h). grid (8, 32). o stored [B,S,E].
__global__ __launch_bounds__(256) void k_av(const float* __restrict__ s,
                                            const float* __restrict__ v,
                                            float* __restrict__ o) {
  const int bh = blockIdx.y;
  const int i0 = blockIdx.x * 64;
  const int b_ = bh >> 3, h = bh & 7;
  __shared__ float At[64][65], Vt[64][65];
  const int tid = threadIdx.x, tx = tid & 15, ty = tid >> 4;
  const float* ab = s + (size_t)bh * SS * SS;
  const float* vb = v + (size_t)bh * SS * HD;
  float acc[4][4] = {};
  for (int j0 = 0; j0 < SS; j0 += 64) {
#pragma unroll
    for (int t = 0; t < 16; ++t) {
      int idx = tid + t * 256;
      int r = idx >> 6, c = idx & 63;
      At[r][c] = ab[(size_t)(i0 + r) * SS + j0 + c];
      Vt[r][c] = vb[(size_t)(j0 + r) * HD + c];
    }
    __syncthreads();
#pragma unroll
    for (int kk = 0; kk < 64; ++kk) {
      float a[4], b[4];
#pragma unroll
      for (int i = 0; i < 4; ++i) a[i] = At[ty + 16 * i][kk];
#pragma unroll
      for (int j = 0; j < 4; ++j) b[j] = Vt[kk][tx + 16 * j];
#pragma unroll
      for (int i = 0; i < 4; ++i)
#pragma unroll
        for (int j = 0; j < 4; ++j) acc[i][j] += a[i] * b[j];
    }
    __syncthreads();
  }
#pragma unroll
  for (int i = 0; i < 4; ++i)
#pragma unroll
    for (int j = 0; j < 4; ++j)
      o[((size_t)b_ * SS + i0 + ty + 16 * i) * EE + h * HD + tx + 16 * j] =
          acc[i][j];
}

// ---------------------------------------------------------------------------
// K8: out-projection o[2048,512] @ Wo + bo -> d_out. grid (8, 32).
__global__ __launch_bounds__(256) void k_out(const float* __restrict__ o,
                                             const float* __restrict__ Wo,
                                             const float* __restrict__ bo,
                                             float* __restrict__ out) {
  const int n0 = blockIdx.x * 64, m0 = blockIdx.y * 64;
  __shared__ float As[64][33];
  __shared__ float Bs[32][65];
  const int tid = threadIdx.x;
  const int tx = tid & 15, ty = tid >> 4;
  float acc[4][4] = {};
  for (int k0 = 0; k0 < EE; k0 += 32) {
#pragma unroll
    for (int t = 0; t < 8; ++t) {
      int idx = tid + t * 256;
      int r = idx >> 5, c = idx & 31;
      As[r][c] = o[(size_t)(m0 + r) * EE + k0 + c];
    }
#pragma unroll
    for (int t = 0; t < 8; ++t) {
      int idx = tid + t * 256;
      int kk = idx >> 6, n = idx & 63;
      Bs[kk][n] = Wo[(size_t)(k0 + kk) * EE + n0 + n];
    }
    __syncthreads();
#pragma unroll
    for (int kk = 0; kk < 32; ++kk) {
      float a[4], b[4];
#pragma unroll
      for (int i = 0; i < 4; ++i) a[i] = As[ty + 16 * i][kk];
#pragma unroll
      for (int j = 0; j < 4; ++j) b[j] = Bs[kk][tx + 16 * j];
#pragma unroll
      for (int i = 0; i < 4; ++i)
#pragma unroll
        for (int j = 0; j < 4; ++j) acc[i][j] += a[i] * b[j];
    }
    __syncthreads();
  }
#pragma unroll
  for (int i = 0; i < 4; ++i)
#pragma unroll
    for (int j = 0; j < 4; ++j) {
      int m = m0 + ty + 16 * i, n = n0 + tx + 16 * j;
      out[(size_t)m * EE + n] = acc[i][j] + bo[n];
    }
}

// ---------------------------------------------------------------------------
extern "C" void kernel_launch(void* const* d_in, const int* in_sizes, int n_in,
                              void* d_out, int out_size, void* d_ws,
                              size_t ws_size, hipStream_t stream) {
  const float* x = (const float*)d_in[0];
  const float* Wq = (const float*)d_in[1];
  const float* bq = (const float*)d_in[2];
  const float* Wk = (const float*)d_in[3];
  const float* bk = (const float*)d_in[4];
  const float* Wv = (const float*)d_in[5];
  const float* bv = (const float*)d_in[6];
  const float* Wo = (const float*)d_in[7];
  const float* bo = (const float*)d_in[8];
  const float* w1 = (const float*)d_in[9];
  const float* b1 = (const float*)d_in[10];
  const float* w2 = (const float*)d_in[11];
  const float* b2 = (const float*)d_in[12];
  const float* tau = (const float*)d_in[13];
  float* out = (float*)d_out;

  float* ws = (float*)d_ws;
  const size_t SZ_QKV = (size_t)BB * NH * SS * HD;  // 1048576
  const size_t SZ_MA = (size_t)BB * SS * SS;        // 1048576
  const size_t SZ_S = (size_t)BB * NH * SS * SS;    // 8388608
  float* q = ws;                       // reused as o after K2
  float* kbuf = q + SZ_QKV;            // reused as t_un after K2
  float* vbuf = kbuf + SZ_QKV;
  float* s = vbuf + SZ_QKV;
  float* ma = s + SZ_S;
  float* acc = ma + SZ_MA;
  float* cst = acc + 32;
  float* t_un = kbuf;  // alias (k dead after k_scores)
  float* o = q;        // alias (q dead after k_scores)

  k_zero<<<1, 64, 0, stream>>>(acc);
  k_qkv<<<dim3(8, 32, 3), 256, 0, stream>>>(x, Wq, bq, Wk, bk, Wv, bv, q, kbuf,
                                            vbuf);
  k_scores<<<dim3(8, 8, 32), 256, 0, stream>>>(q, kbuf, s);
  k_ma<<<dim3(1024), 256, 0, stream>>>(s, ma);
  k_transform<<<dim3(2048), 256, 0, stream>>>(ma, w1, b1, w2, b2, t_un, acc);
  k_consts<<<1, 64, 0, stream>>>(acc, cst);
  k_blend<<<dim3(512, 32), 256, 0, stream>>>(s, ma, t_un, cst, tau);
  k_av<<<dim3(8, 32), 256, 0, stream>>>(s, vbuf, o);
  k_out<<<dim3(8, 32), 256, 0, stream>>>(o, Wo, bo, out);
}

// Round 2
// 266.244 us; speedup vs baseline: 1.7719x; 1.7719x over previous
//
#include <hip/hip_runtime.h>
#include <math.h>

// Problem constants (fixed by setup_inputs)
#define BB 4
#define SS 512
#define EE 512
#define NH 8
#define HD 64
#define NC 128
#define NTAB 4096  // table intervals over sa in [-0.4, 0.4]

typedef __attribute__((ext_vector_type(8))) __bf16 bf16x8;
typedef __attribute__((ext_vector_type(4))) float f32x4;

__device__ __forceinline__ float clampf(float v, float lo, float hi) {
  return fminf(fmaxf(v, lo), hi);
}
__device__ __forceinline__ unsigned short bf16_rn(float x) {
  unsigned int u = __float_as_uint(x);
  unsigned int r = u + 0x7fffu + ((u >> 16) & 1u);
  return (unsigned short)(r >> 16);
}
__device__ __forceinline__ float bf16_tof(unsigned short h) {
  return __uint_as_float(((unsigned int)h) << 16);
}

__device__ __forceinline__ float waveRedSum(float v) {
#pragma unroll
  for (int o = 32; o; o >>= 1) v += __shfl_xor(v, o);
  return v;
}
__device__ __forceinline__ float waveRedMax(float v) {
#pragma unroll
  for (int o = 32; o; o >>= 1) v = fmaxf(v, __shfl_xor(v, o));
  return v;
}
// blockDim.x == 256 (4 waves) assumed
__device__ __forceinline__ float blockRedSum(float v, float* red) {
  int tid = threadIdx.x;
  v = waveRedSum(v);
  __syncthreads();
  if ((tid & 63) == 0) red[tid >> 6] = v;
  __syncthreads();
  return red[0] + red[1] + red[2] + red[3];
}
__device__ __forceinline__ float blockRedMax(float v, float* red) {
  int tid = threadIdx.x;
  v = waveRedMax(v);
  __syncthreads();
  if ((tid & 63) == 0) red[tid >> 6] = v;
  __syncthreads();
  return fmaxf(fmaxf(red[0], red[1]), fmaxf(red[2], red[3]));
}

// ---------------------------------------------------------------------------
// K_table: tabulate g(sa) = sigmoid(clip(1 + 0.05*(50*ap(sa)), 0.5, 1.5))
// where ap(sa) = clip(sum_c relu(clip(sa*w1c+b1c,-5,5))*w2c + b2, -5, 5).
// Piecewise-linear in sa except sigmoid curvature; 4097-point linear interp.
__global__ void k_table(const float* __restrict__ w1,
                        const float* __restrict__ b1,
                        const float* __restrict__ w2,
                        const float* __restrict__ b2, float* __restrict__ T) {
  int idx = blockIdx.x * 256 + threadIdx.x;
  if (idx > NTAB) return;
  float sa = -0.4f + (float)idx * (0.8f / (float)NTAB);
  float ap = 0.f;
#pragma unroll 4
  for (int c = 0; c < NC; ++c) {
    float h = fminf(fmaxf(sa * w1[c] + b1[c], 0.f), 5.f);
    ap += h * w2[c];
  }
  ap = clampf(ap + b2[0], -5.f, 5.f);
  float tay = clampf(1.0f + 0.05f * (ap * 50.0f), 0.5f, 1.5f);
  T[idx] = 1.0f / (1.0f + expf(-tay));
}

// ---------------------------------------------------------------------------
// K1: fused QKV projection. x[2048,512] @ W[512,512] + b. q,k stored as split
// bf16 (hi + lo) in [B,H,S,HD]; v stored fp32. grid (8, 32, 3), block 256.
__global__ __launch_bounds__(256) void k_qkv(
    const float* __restrict__ x,
    const float* __restrict__ Wq, const float* __restrict__ bq,
    const float* __restrict__ Wk, const float* __restrict__ bk,
    const float* __restrict__ Wv, const float* __restrict__ bv,
    unsigned short* __restrict__ qh, unsigned short* __restrict__ ql,
    unsigned short* __restrict__ kh, unsigned short* __restrict__ kl,
    float* __restrict__ v) {
  const int which = blockIdx.z;
  const float* W = (which == 0) ? Wq : (which == 1) ? Wk : Wv;
  const float* bias = (which == 0) ? bq : (which == 1) ? bk : bv;
  const int n0 = blockIdx.x * 64, m0 = blockIdx.y * 64;
  __shared__ float As[64][33];
  __shared__ float Bs[32][65];
  const int tid = threadIdx.x;
  const int tx = tid & 15, ty = tid >> 4;
  float acc[4][4] = {};
  for (int k0 = 0; k0 < EE; k0 += 32) {
#pragma unroll
    for (int t = 0; t < 8; ++t) {
      int idx = tid + t * 256;
      int r = idx >> 5, c = idx & 31;
      As[r][c] = x[(m0 + r) * EE + k0 + c];
    }
#pragma unroll
    for (int t = 0; t < 8; ++t) {
      int idx = tid + t * 256;
      int kk = idx >> 6, n = idx & 63;
      Bs[kk][n] = W[(k0 + kk) * EE + n0 + n];
    }
    __syncthreads();
#pragma unroll
    for (int kk = 0; kk < 32; ++kk) {
      float a[4], b[4];
#pragma unroll
      for (int i = 0; i < 4; ++i) a[i] = As[ty + 16 * i][kk];
#pragma unroll
      for (int j = 0; j < 4; ++j) b[j] = Bs[kk][tx + 16 * j];
#pragma unroll
      for (int i = 0; i < 4; ++i)
#pragma unroll
        for (int j = 0; j < 4; ++j) acc[i][j] += a[i] * b[j];
    }
    __syncthreads();
  }
#pragma unroll
  for (int i = 0; i < 4; ++i) {
    int m = m0 + ty + 16 * i;        // global row = b*S + si
    int b_ = m >> 9, si = m & 511;
#pragma unroll
    for (int j = 0; j < 4; ++j) {
      int n = n0 + tx + 16 * j;      // = head*64 + d
      int hh = n >> 6, d = n & 63;
      size_t idx = (((size_t)(b_ * NH + hh) * SS) + si) * HD + d;
      float val = acc[i][j] + bias[n];
      if (which == 2) {
        v[idx] = val;
      } else {
        unsigned short* dh = which ? kh : qh;
        unsigned short* dl = which ? kl : ql;
        unsigned short hb = bf16_rn(val);
        dh[idx] = hb;
        dl[idx] = bf16_rn(val - bf16_tof(hb));
      }
    }
  }
}

// ---------------------------------------------------------------------------
// K2: scores via split-bf16 MFMA: s = clip(q.k^T * 0.125, -15, 15).
// grid (8 nTiles, 8 mTiles, 32 bh), block 256 = 4 waves.
// Wave w computes rows [i0+16w, i0+16w+16) x cols [j0, j0+64).
// Layouts (HW-verified): A/B frag [idx=lane&15][k=(lane>>4)*8+j],
// C/D: col=lane&15, row=(lane>>4)*4+reg.
__global__ __launch_bounds__(256) void k_scores_mfma(
    const unsigned short* __restrict__ qh, const unsigned short* __restrict__ ql,
    const unsigned short* __restrict__ kh, const unsigned short* __restrict__ kl,
    float* __restrict__ s) {
  const int bh = blockIdx.z;
  const int i0 = blockIdx.y * 64, j0 = blockIdx.x * 64;
  const int tid = threadIdx.x;
  const int wave = tid >> 6, lane = tid & 63;
  const int quad = lane >> 4, l16 = lane & 15;

  const size_t qoff = ((size_t)bh * SS + i0 + wave * 16 + l16) * HD + quad * 8;
  bf16x8 a_hi[2], a_lo[2];
#pragma unroll
  for (int ks = 0; ks < 2; ++ks) {
    a_hi[ks] = *reinterpret_cast<const bf16x8*>(qh + qoff + ks * 32);
    a_lo[ks] = *reinterpret_cast<const bf16x8*>(ql + qoff + ks * 32);
  }
  bf16x8 b_hi[4][2], b_lo[4][2];
#pragma unroll
  for (int t = 0; t < 4; ++t) {
    const size_t koff =
        ((size_t)bh * SS + j0 + t * 16 + l16) * HD + quad * 8;
#pragma unroll
    for (int ks = 0; ks < 2; ++ks) {
      b_hi[t][ks] = *reinterpret_cast<const bf16x8*>(kh + koff + ks * 32);
      b_lo[t][ks] = *reinterpret_cast<const bf16x8*>(kl + koff + ks * 32);
    }
  }
  f32x4 acc[4] = {{0.f, 0.f, 0.f, 0.f},
                  {0.f, 0.f, 0.f, 0.f},
                  {0.f, 0.f, 0.f, 0.f},
                  {0.f, 0.f, 0.f, 0.f}};
#pragma unroll
  for (int ks = 0; ks < 2; ++ks) {
#pragma unroll
    for (int t = 0; t < 4; ++t) {
      acc[t] = __builtin_amdgcn_mfma_f32_16x16x32_bf16(a_hi[ks], b_hi[t][ks],
                                                       acc[t], 0, 0, 0);
      acc[t] = __builtin_amdgcn_mfma_f32_16x16x32_bf16(a_hi[ks], b_lo[t][ks],
                                                       acc[t], 0, 0, 0);
      acc[t] = __builtin_amdgcn_mfma_f32_16x16x32_bf16(a_lo[ks], b_hi[t][ks],
                                                       acc[t], 0, 0, 0);
    }
  }
  float* sb = s + (size_t)bh * SS * SS;
#pragma unroll
  for (int t = 0; t < 4; ++t) {
#pragma unroll
    for (int r = 0; r < 4; ++r) {
      float val = acc[t][r] * 0.125f;
      val = clampf(val, -15.0f, 15.0f);  // inputs finite: nan_to_num is identity
      sb[(size_t)(i0 + wave * 16 + quad * 4 + r) * SS + j0 + t * 16 + l16] = val;
    }
  }
}

// ---------------------------------------------------------------------------
// K3: per-row fused ma + autopoietic transform. One 64-lane wave per row
// (b,i): ma = mean_h s; p-softmax (no max-sub: |mc|<=10 so exp<=2.2e4 safe);
// entropy H; Fm-softmax (3H in [0,1.11], no max-sub); sig via table; t=sig*F.
// Writes ma row, t row, and 6 per-row partials. grid 2048, block 64.
__global__ __launch_bounds__(64) void k_rowstat(
    const float* __restrict__ s, const float* __restrict__ T,
    float* __restrict__ ma, float* __restrict__ t_un,
    float* __restrict__ rowred) {
  const int row = blockIdx.x;     // b*S + i
  const int b_ = row >> 9, i = row & 511;
  const int lane = threadIdx.x;

  float4 a0 = {0.f, 0.f, 0.f, 0.f}, a1 = {0.f, 0.f, 0.f, 0.f};
#pragma unroll
  for (int hh = 0; hh < NH; ++hh) {
    const float4* p = reinterpret_cast<const float4*>(
                          s + (((size_t)(b_ * NH + hh) * SS) + i) * SS) +
                      lane * 2;
    float4 u0 = p[0], u1 = p[1];
    a0.x += u0.x; a0.y += u0.y; a0.z += u0.z; a0.w += u0.w;
    a1.x += u1.x; a1.y += u1.y; a1.z += u1.z; a1.w += u1.w;
  }
  float m[8] = {a0.x * 0.125f, a0.y * 0.125f, a0.z * 0.125f, a0.w * 0.125f,
                a1.x * 0.125f, a1.y * 0.125f, a1.z * 0.125f, a1.w * 0.125f};
  // write ma row
  {
    float4* mp = reinterpret_cast<float4*>(ma + ((size_t)b_ * SS + i) * SS) +
                 lane * 2;
    float4 w0 = {m[0], m[1], m[2], m[3]}, w1v = {m[4], m[5], m[6], m[7]};
    mp[0] = w0;
    mp[1] = w1v;
  }
  // stats on ma
  float sma = 0.f, sma2 = 0.f, mabs = 0.f;
#pragma unroll
  for (int e = 0; e < 8; ++e) {
    sma += m[e];
    sma2 += m[e] * m[e];
    mabs = fmaxf(mabs, fabsf(m[e]));
  }
  sma = waveRedSum(sma);
  sma2 = waveRedSum(sma2);
  mabs = waveRedMax(mabs);

  // p = softmax(clip(ma,-10,10)) without max subtraction
  float ex[8], esum = 0.f;
#pragma unroll
  for (int e = 0; e < 8; ++e) {
    ex[e] = expf(clampf(m[e], -10.f, 10.f));
    esum += ex[e];
  }
  esum = waveRedSum(esum);
  float inv = 1.0f / esum;
  float Hv[8], sH = 0.f;
#pragma unroll
  for (int e = 0; e < 8; ++e) {
    float p = ex[e] * inv;
    Hv[e] = -p * logf(p + 1e-6f);
    sH += Hv[e];
  }
  sH = waveRedSum(sH);

  // Fm = softmax(3*H); 3H in [0,~1.11], no max subtraction needed
  float fx[8], fsum = 0.f;
#pragma unroll
  for (int e = 0; e < 8; ++e) {
    fx[e] = expf(3.0f * Hv[e]);
    fsum += fx[e];
  }
  fsum = waveRedSum(fsum);
  float finv = 1.0f / fsum;

  // sig via table lookup on sa = clip(ma,-8,8)*0.05 in [-0.4,0.4]
  float t[8], st = 0.f, st2 = 0.f;
#pragma unroll
  for (int e = 0; e < 8; ++e) {
    float sa = clampf(m[e], -8.f, 8.f) * 0.05f;
    float pos = (sa + 0.4f) * ((float)NTAB / 0.8f);
    int idx = (int)pos;
    idx = idx < 0 ? 0 : (idx > NTAB - 1 ? NTAB - 1 : idx);
    float frac = pos - (float)idx;
    float g0 = T[idx], g1 = T[idx + 1];
    float sig = g0 + (g1 - g0) * frac;
    t[e] = sig * fx[e] * finv;
    st += t[e];
    st2 += t[e] * t[e];
  }
  st = waveRedSum(st);
  st2 = waveRedSum(st2);
  {
    float4* tp = reinterpret_cast<float4*>(t_un + ((size_t)b_ * SS + i) * SS) +
                 lane * 2;
    float4 w0 = {t[0], t[1], t[2], t[3]}, w1v = {t[4], t[5], t[6], t[7]};
    tp[0] = w0;
    tp[1] = w1v;
  }
  if (lane == 0) {
    float* rp = rowred + (size_t)row * 8;
    rp[0] = sma; rp[1] = sma2; rp[2] = mabs;
    rp[3] = st;  rp[4] = st2;  rp[5] = sH;
  }
}

// ---------------------------------------------------------------------------
// K4: reduce per-row partials -> per-batch blend constants c0,c1,c2.
// grid 4 (one per batch), block 256 (each thread 2 rows).
__global__ __launch_bounds__(256) void k_consts(
    const float* __restrict__ rowred, float* __restrict__ cst) {
  const int b_ = blockIdx.x;
  const int tid = threadIdx.x;
  __shared__ float red[4];
  const float* r0 = rowred + ((size_t)b_ * SS + tid * 2) * 8;
  const float* r1 = r0 + 8;
  float sma = blockRedSum(r0[0] + r1[0], red);
  float sma2 = blockRedSum(r0[1] + r1[1], red);
  float mabs = blockRedMax(fmaxf(r0[2], r1[2]), red);
  float st = blockRedSum(r0[3] + r1[3], red);
  float st2 = blockRedSum(r0[4] + r1[4], red);
  float sH = blockRedSum(r0[5] + r1[5], red);
  if (tid == 0) {
    const float N = (float)(SS * SS);
    float eo = sqrtf(sma2) + 1e-4f;
    float et = sqrtf(st2) + 1e-4f;
    float r = clampf(eo / et, 0.8f, 1.2f);
    float tmean = r * st / N;
    float om = sma / N;
    float vart = r * r * fmaxf(st2 / N - (st / N) * (st / N), 0.f);
    float tstd = sqrtf(fmaxf(vart, 0.01f));
    float varo = fmaxf(sma2 / N - om * om, 0.f);
    float ostd = sqrtf(fmaxf(varo, 0.01f));
    float gd = clampf(ostd / tstd, 0.8f, 1.2f);
    float ar = clampf(mabs, 1.f, 10.f);
    float sm = clampf(0.3f / log1pf(ar), 0.1f, 0.5f);
    float ent = sH / N;
    float ne = ent / logf((float)SS);
    float rr = 0.4f * (1.f - clampf(ne, 0.f, 0.4f));
    float G = sm * gd;
    cst[b_ * 4 + 0] = rr * (1.f - G) * tmean;  // c0
    cst[b_ * 4 + 1] = rr * G * r;              // c1 (multiplies t_un)
    cst[b_ * 4 + 2] = rr;                      // c2 (multiplies ma)
  }
}

// ---------------------------------------------------------------------------
// K5: blend + row softmax, in-place s -> attn. grid (512, 32), block 256.
__global__ __launch_bounds__(256) void k_blend(
    float* __restrict__ s, const float* __restrict__ ma,
    const float* __restrict__ t_un, const float* __restrict__ cst,
    const float* __restrict__ tau) {
  const int i = blockIdx.x;
  const int bh = blockIdx.y;
  const int b_ = bh >> 3;
  const int tid = threadIdx.x;
  __shared__ float red[4];
  const float c0 = cst[b_ * 4 + 0], c1 = cst[b_ * 4 + 1], c2 = cst[b_ * 4 + 2];
  const float itau = 1.0f / tau[0];
  float* srow = s + ((size_t)bh * SS + i) * SS;
  const float* mrow = ma + ((size_t)b_ * SS + i) * SS;
  const float* trow = t_un + ((size_t)b_ * SS + i) * SS;
  float v0 = (srow[tid] + c0 + c1 * trow[tid] - c2 * mrow[tid]) * itau;
  float v1 = (srow[tid + 256] + c0 + c1 * trow[tid + 256] - c2 * mrow[tid + 256]) * itau;
  float mx = blockRedMax(fmaxf(v0, v1), red);
  float e0 = expf(v0 - mx), e1 = expf(v1 - mx);
  float sum = blockRedSum(e0 + e1, red);
  float inv = 1.0f / sum;
  srow[tid] = e0 * inv;
  srow[tid + 256] = e1 * inv;
}

// ---------------------------------------------------------------------------
// K6: out = attn @ v per (b,h). grid (8, 32). o stored [B,S,E].
__global__ __launch_bounds__(256) void k_av(const float* __restrict__ s,
                                            const float* __restrict__ v,
                                            float* __restrict__ o) {
  const int bh = blockIdx.y;
  const int i0 = blockIdx.x * 64;
  const int b_ = bh >> 3, h = bh & 7;
  __shared__ float At[64][65], Vt[64][65];
  const int tid = threadIdx.x, tx = tid & 15, ty = tid >> 4;
  const float* ab = s + (size_t)bh * SS * SS;
  const float* vb = v + (size_t)bh * SS * HD;
  float acc[4][4] = {};
  for (int j0 = 0; j0 < SS; j0 += 64) {
#pragma unroll
    for (int t = 0; t < 16; ++t) {
      int idx = tid + t * 256;
      int r = idx >> 6, c = idx & 63;
      At[r][c] = ab[(size_t)(i0 + r) * SS + j0 + c];
      Vt[r][c] = vb[(size_t)(j0 + r) * HD + c];
    }
    __syncthreads();
#pragma unroll
    for (int kk = 0; kk < 64; ++kk) {
      float a[4], b[4];
#pragma unroll
      for (int i = 0; i < 4; ++i) a[i] = At[ty + 16 * i][kk];
#pragma unroll
      for (int j = 0; j < 4; ++j) b[j] = Vt[kk][tx + 16 * j];
#pragma unroll
      for (int i = 0; i < 4; ++i)
#pragma unroll
        for (int j = 0; j < 4; ++j) acc[i][j] += a[i] * b[j];
    }
    __syncthreads();
  }
#pragma unroll
  for (int i = 0; i < 4; ++i)
#pragma unroll
    for (int j = 0; j < 4; ++j)
      o[((size_t)b_ * SS + i0 + ty + 16 * i) * EE + h * HD + tx + 16 * j] =
          acc[i][j];
}

// ---------------------------------------------------------------------------
// K7: out-projection o[2048,512] @ Wo + bo -> d_out. grid (8, 32).
__global__ __launch_bounds__(256) void k_out(const float* __restrict__ o,
                                             const float* __restrict__ Wo,
                                             const float* __restrict__ bo,
                                             float* __restrict__ out) {
  const int n0 = blockIdx.x * 64, m0 = blockIdx.y * 64;
  __shared__ float As[64][33];
  __shared__ float Bs[32][65];
  const int tid = threadIdx.x;
  const int tx = tid & 15, ty = tid >> 4;
  float acc[4][4] = {};
  for (int k0 = 0; k0 < EE; k0 += 32) {
#pragma unroll
    for (int t = 0; t < 8; ++t) {
      int idx = tid + t * 256;
      int r = idx >> 5, c = idx & 31;
      As[r][c] = o[(size_t)(m0 + r) * EE + k0 + c];
    }
#pragma unroll
    for (int t = 0; t < 8; ++t) {
      int idx = tid + t * 256;
      int kk = idx >> 6, n = idx & 63;
      Bs[kk][n] = Wo[(size_t)(k0 + kk) * EE + n0 + n];
    }
    __syncthreads();
#pragma unroll
    for (int kk = 0; kk < 32; ++kk) {
      float a[4], b[4];
#pragma unroll
      for (int i = 0; i < 4; ++i) a[i] = As[ty + 16 * i][kk];
#pragma unroll
      for (int j = 0; j < 4; ++j) b[j] = Bs[kk][tx + 16 * j];
#pragma unroll
      for (int i = 0; i < 4; ++i)
#pragma unroll
        for (int j = 0; j < 4; ++j) acc[i][j] += a[i] * b[j];
    }
    __syncthreads();
  }
#pragma unroll
  for (int i = 0; i < 4; ++i)
#pragma unroll
    for (int j = 0; j < 4; ++j) {
      int m = m0 + ty + 16 * i, n = n0 + tx + 16 * j;
      out[(size_t)m * EE + n] = acc[i][j] + bo[n];
    }
}

// ---------------------------------------------------------------------------
extern "C" void kernel_launch(void* const* d_in, const int* in_sizes, int n_in,
                              void* d_out, int out_size, void* d_ws,
                              size_t ws_size, hipStream_t stream) {
  const float* x = (const float*)d_in[0];
  const float* Wq = (const float*)d_in[1];
  const float* bq = (const float*)d_in[2];
  const float* Wk = (const float*)d_in[3];
  const float* bk = (const float*)d_in[4];
  const float* Wv = (const float*)d_in[5];
  const float* bv = (const float*)d_in[6];
  const float* Wo = (const float*)d_in[7];
  const float* bo = (const float*)d_in[8];
  const float* w1 = (const float*)d_in[9];
  const float* b1 = (const float*)d_in[10];
  const float* w2 = (const float*)d_in[11];
  const float* b2 = (const float*)d_in[12];
  const float* tau = (const float*)d_in[13];
  float* out = (float*)d_out;

  float* ws = (float*)d_ws;
  const size_t NQK = (size_t)BB * NH * SS * HD;  // 1048576 elements
  // bf16 split q/k: 4 x (NQK ushort) = 2M floats worth
  unsigned short* qh = (unsigned short*)ws;
  unsigned short* ql = qh + NQK;
  unsigned short* kh = ql + NQK;
  unsigned short* kl = kh + NQK;
  float* v = ws + 2 * (NQK / 2) * 2;            // = ws + 2M floats
  float* s = v + NQK;                           // 8.39M floats
  float* ma = s + (size_t)BB * NH * SS * SS;    // 1M floats
  float* T = ma + (size_t)BB * SS * SS;         // 4097 (pad 8192)
  float* rowred = T + 8192;                     // 2048*8
  float* cst = rowred + 2048 * 8;               // 16
  float* t_un = (float*)kh;  // alias: kh/kl dead after k_scores (4 MB)
  float* o = (float*)qh;     // alias: qh/ql dead after k_scores (4 MB)

  k_table<<<17, 256, 0, stream>>>(w1, b1, w2, b2, T);
  k_qkv<<<dim3(8, 32, 3), 256, 0, stream>>>(x, Wq, bq, Wk, bk, Wv, bv, qh, ql,
                                            kh, kl, v);
  k_scores_mfma<<<dim3(8, 8, 32), 256, 0, stream>>>(qh, ql, kh, kl, s);
  k_rowstat<<<2048, 64, 0, stream>>>(s, T, ma, t_un, rowred);
  k_consts<<<4, 256, 0, stream>>>(rowred, cst);
  k_blend<<<dim3(512, 32), 256, 0, stream>>>(s, ma, t_un, cst, tau);
  k_av<<<dim3(8, 32), 256, 0, stream>>>(s, v, o);
  k_out<<<dim3(8, 32), 256, 0, stream>>>(o, Wo, bo, out);
}

// Round 4
// 256.180 us; speedup vs baseline: 1.8415x; 1.0393x over previous
//
#include <hip/hip_runtime.h>
#include <math.h>

// Problem constants (fixed by setup_inputs)
#define BB 4
#define SS 512
#define EE 512
#define NH 8
#define HD 64
#define NC 128
#define NTAB 4096  // table intervals over sa in [-0.4, 0.4]

typedef _Float16 f16x8 __attribute__((ext_vector_type(8)));
typedef float f32x4 __attribute__((ext_vector_type(4)));

struct HL { _Float16 h, l; };

__device__ __forceinline__ float clampf(float v, float lo, float hi) {
  return fminf(fmaxf(v, lo), hi);
}
__device__ __forceinline__ HL split16(float x) {
  HL r;
  r.h = (_Float16)x;
  r.l = (_Float16)(x - (float)r.h);
  return r;
}

__device__ __forceinline__ float waveRedSum(float v) {
#pragma unroll
  for (int o = 32; o; o >>= 1) v += __shfl_xor(v, o);
  return v;
}
__device__ __forceinline__ float waveRedMax(float v) {
#pragma unroll
  for (int o = 32; o; o >>= 1) v = fmaxf(v, __shfl_xor(v, o));
  return v;
}
// blockDim.x == 256 (4 waves) assumed
__device__ __forceinline__ float blockRedSum(float v, float* red) {
  int tid = threadIdx.x;
  v = waveRedSum(v);
  __syncthreads();
  if ((tid & 63) == 0) red[tid >> 6] = v;
  __syncthreads();
  return red[0] + red[1] + red[2] + red[3];
}
__device__ __forceinline__ float blockRedMax(float v, float* red) {
  int tid = threadIdx.x;
  v = waveRedMax(v);
  __syncthreads();
  if ((tid & 63) == 0) red[tid >> 6] = v;
  __syncthreads();
  return fmaxf(fmaxf(red[0], red[1]), fmaxf(red[2], red[3]));
}

// ---------------------------------------------------------------------------
// K_table: tabulate g(sa) = sigmoid(clip(1 + 2.5*ap(sa), 0.5, 1.5)).
__global__ void k_table(const float* __restrict__ w1,
                        const float* __restrict__ b1,
                        const float* __restrict__ w2,
                        const float* __restrict__ b2, float* __restrict__ T) {
  int idx = blockIdx.x * 256 + threadIdx.x;
  if (idx > NTAB) return;
  float sa = -0.4f + (float)idx * (0.8f / (float)NTAB);
  float ap = 0.f;
#pragma unroll 4
  for (int c = 0; c < NC; ++c) {
    float h = fminf(fmaxf(sa * w1[c] + b1[c], 0.f), 5.f);
    ap += h * w2[c];
  }
  ap = clampf(ap + b2[0], -5.f, 5.f);
  float tay = clampf(1.0f + 0.05f * (ap * 50.0f), 0.5f, 1.5f);
  T[idx] = 1.0f / (1.0f + expf(-tay));
}

// ---------------------------------------------------------------------------
// K_split_x: x fp32 [2048*512] -> f16 hi/lo. 512 blocks x 256, 8 elems/thread.
__global__ __launch_bounds__(256) void k_split_x(const float* __restrict__ x,
                                                 _Float16* __restrict__ xh,
                                                 _Float16* __restrict__ xl) {
  int idx = (blockIdx.x * 256 + threadIdx.x) * 8;
  float4 u0 = *(const float4*)(x + idx);
  float4 u1 = *(const float4*)(x + idx + 4);
  float f[8] = {u0.x, u0.y, u0.z, u0.w, u1.x, u1.y, u1.z, u1.w};
  f16x8 h, l;
#pragma unroll
  for (int j = 0; j < 8; ++j) {
    HL r = split16(f[j]);
    h[j] = r.h;
    l[j] = r.l;
  }
  *(f16x8*)(xh + idx) = h;
  *(f16x8*)(xl + idx) = l;
}

// ---------------------------------------------------------------------------
// K_split_wt: W[512k][512n] -> Wt hi/lo [n][k] f16, 4 matrices (q,k,v,o).
// 64x64 LDS tile transpose. grid (8 ktile, 8 ntile, 4 mat), block 256.
__global__ __launch_bounds__(256) void k_split_wt(
    const float* __restrict__ Wq, const float* __restrict__ Wk,
    const float* __restrict__ Wv, const float* __restrict__ Wo,
    _Float16* __restrict__ Wth, _Float16* __restrict__ Wtl) {
  const int z = blockIdx.z;
  const float* W = (z == 0) ? Wq : (z == 1) ? Wk : (z == 2) ? Wv : Wo;
  const int k0 = blockIdx.x * 64, n0 = blockIdx.y * 64;
  __shared__ float T[64][68];
  const int tid = threadIdx.x;
  const int r = tid >> 2, c = (tid & 3) * 16;
#pragma unroll
  for (int j = 0; j < 16; j += 4)
    *(float4*)&T[r][c + j] = *(const float4*)(W + (size_t)(k0 + r) * EE + n0 + c + j);
  __syncthreads();
  // transposed read: thread handles output row (n0+r), k chunk c..c+15
  f16x8 h0, l0, h1, l1;
#pragma unroll
  for (int j = 0; j < 8; ++j) {
    HL r0 = split16(T[c + j][r]);
    HL r1 = split16(T[c + 8 + j][r]);
    h0[j] = r0.h; l0[j] = r0.l;
    h1[j] = r1.h; l1[j] = r1.l;
  }
  _Float16* dh = Wth + ((size_t)z * EE + n0 + r) * EE + k0 + c;
  _Float16* dl = Wtl + ((size_t)z * EE + n0 + r) * EE + k0 + c;
  *(f16x8*)dh = h0;
  *(f16x8*)(dh + 8) = h1;
  *(f16x8*)dl = l0;
  *(f16x8*)(dl + 8) = l1;
}

// ---------------------------------------------------------------------------
// K_vt: v fp32 [bh][si][64] -> v_t hi/lo f16 [bh][64][si]. grid (8 si-tile, 32 bh).
__global__ __launch_bounds__(256) void k_vt(const float* __restrict__ v,
                                            _Float16* __restrict__ vth,
                                            _Float16* __restrict__ vtl) {
  const int bh = blockIdx.y;
  const int si0 = blockIdx.x * 64;
  __shared__ float T[64][68];
  const int tid = threadIdx.x;
  const int r = tid >> 2, c = (tid & 3) * 16;
#pragma unroll
  for (int j = 0; j < 16; j += 4)
    *(float4*)&T[r][c + j] =
        *(const float4*)(v + ((size_t)bh * SS + si0 + r) * HD + c + j);
  __syncthreads();
  f16x8 h0, l0, h1, l1;
#pragma unroll
  for (int j = 0; j < 8; ++j) {
    HL r0 = split16(T[c + j][r]);
    HL r1 = split16(T[c + 8 + j][r]);
    h0[j] = r0.h; l0[j] = r0.l;
    h1[j] = r1.h; l1[j] = r1.l;
  }
  _Float16* dh = vth + ((size_t)bh * HD + r) * SS + si0 + c;
  _Float16* dl = vtl + ((size_t)bh * HD + r) * SS + si0 + c;
  *(f16x8*)dh = h0;
  *(f16x8*)(dh + 8) = h1;
  *(f16x8*)dl = l0;
  *(f16x8*)(dl + 8) = l1;
}

// ---------------------------------------------------------------------------
// K_qkv: MFMA 3-term f16 GEMM x[2048,512] @ W -> q,k split f16 [bh][si][d];
// v fp32 [bh][si][d]. grid (4 nb, 32 mb, 3 which), block 256 (2x2 waves of
// 32m x 64n).
__global__ __launch_bounds__(256) void k_qkv_mfma(
    const _Float16* __restrict__ xh, const _Float16* __restrict__ xl,
    const _Float16* __restrict__ Wth, const _Float16* __restrict__ Wtl,
    const float* __restrict__ bq, const float* __restrict__ bk,
    const float* __restrict__ bv,
    _Float16* __restrict__ qh, _Float16* __restrict__ ql,
    _Float16* __restrict__ kh, _Float16* __restrict__ kl,
    float* __restrict__ v) {
  const int which = blockIdx.z;
  const int tid = threadIdx.x;
  const int wave = tid >> 6, lane = tid & 63;
  const int quad = lane >> 4, l16 = lane & 15;
  const int m0 = blockIdx.y * 64 + (wave >> 1) * 32;
  const int n0 = blockIdx.x * 128 + (wave & 1) * 64;
  const _Float16* Bh = Wth + (size_t)which * EE * EE;
  const _Float16* Bl = Wtl + (size_t)which * EE * EE;

  f32x4 acc[2][4] = {};
  for (int k0 = 0; k0 < EE; k0 += 32) {
    f16x8 ah[2], al[2];
#pragma unroll
    for (int mt = 0; mt < 2; ++mt) {
      const size_t off = (size_t)(m0 + mt * 16 + l16) * EE + k0 + quad * 8;
      ah[mt] = *(const f16x8*)(xh + off);
      al[mt] = *(const f16x8*)(xl + off);
    }
    f16x8 bhf[4], blf[4];
#pragma unroll
    for (int nt = 0; nt < 4; ++nt) {
      const size_t off = (size_t)(n0 + nt * 16 + l16) * EE + k0 + quad * 8;
      bhf[nt] = *(const f16x8*)(Bh + off);
      blf[nt] = *(const f16x8*)(Bl + off);
    }
#pragma unroll
    for (int mt = 0; mt < 2; ++mt)
#pragma unroll
      for (int nt = 0; nt < 4; ++nt) {
        acc[mt][nt] = __builtin_amdgcn_mfma_f32_16x16x32_f16(ah[mt], bhf[nt],
                                                             acc[mt][nt], 0, 0, 0);
        acc[mt][nt] = __builtin_amdgcn_mfma_f32_16x16x32_f16(ah[mt], blf[nt],
                                                             acc[mt][nt], 0, 0, 0);
        acc[mt][nt] = __builtin_amdgcn_mfma_f32_16x16x32_f16(al[mt], bhf[nt],
                                                             acc[mt][nt], 0, 0, 0);
      }
  }
  const float* bias = (which == 0) ? bq : (which == 1) ? bk : bv;
#pragma unroll
  for (int mt = 0; mt < 2; ++mt) {
    const int mbase = m0 + mt * 16 + quad * 4;
#pragma unroll
    for (int nt = 0; nt < 4; ++nt) {
      const int col = n0 + nt * 16 + l16;
      const float bb = bias[col];
      const int hh = col >> 6, d = col & 63;
#pragma unroll
      for (int r = 0; r < 4; ++r) {
        const int mm = mbase + r;
        const int b_ = mm >> 9, si = mm & 511;
        const size_t idx = (((size_t)(b_ * NH + hh)) * SS + si) * HD + d;
        const float val = acc[mt][nt][r] + bb;
        if (which == 2) {
          v[idx] = val;
        } else {
          HL sp = split16(val);
          (which ? kh : qh)[idx] = sp.h;
          (which ? kl : ql)[idx] = sp.l;
        }
      }
    }
  }
}

// ---------------------------------------------------------------------------
// K_scores: s = clip(q.k^T * 0.125, -15, 15) via 3-term f16 MFMA.
// grid (8 nTiles, 8 mTiles, 32 bh), block 256 (4 waves stacked in m).
__global__ __launch_bounds__(256) void k_scores_mfma(
    const _Float16* __restrict__ qh, const _Float16* __restrict__ ql,
    const _Float16* __restrict__ kh, const _Float16* __restrict__ kl,
    float* __restrict__ s) {
  const int bh = blockIdx.z;
  const int i0 = blockIdx.y * 64, j0 = blockIdx.x * 64;
  const int tid = threadIdx.x;
  const int wave = tid >> 6, lane = tid & 63;
  const int quad = lane >> 4, l16 = lane & 15;

  const size_t qoff = ((size_t)bh * SS + i0 + wave * 16 + l16) * HD + quad * 8;
  f16x8 a_hi[2], a_lo[2];
#pragma unroll
  for (int ks = 0; ks < 2; ++ks) {
    a_hi[ks] = *(const f16x8*)(qh + qoff + ks * 32);
    a_lo[ks] = *(const f16x8*)(ql + qoff + ks * 32);
  }
  f16x8 b_hi[4][2], b_lo[4][2];
#pragma unroll
  for (int t = 0; t < 4; ++t) {
    const size_t koff = ((size_t)bh * SS + j0 + t * 16 + l16) * HD + quad * 8;
#pragma unroll
    for (int ks = 0; ks < 2; ++ks) {
      b_hi[t][ks] = *(const f16x8*)(kh + koff + ks * 32);
      b_lo[t][ks] = *(const f16x8*)(kl + koff + ks * 32);
    }
  }
  f32x4 acc[4] = {};
#pragma unroll
  for (int ks = 0; ks < 2; ++ks) {
#pragma unroll
    for (int t = 0; t < 4; ++t) {
      acc[t] = __builtin_amdgcn_mfma_f32_16x16x32_f16(a_hi[ks], b_hi[t][ks],
                                                      acc[t], 0, 0, 0);
      acc[t] = __builtin_amdgcn_mfma_f32_16x16x32_f16(a_hi[ks], b_lo[t][ks],
                                                      acc[t], 0, 0, 0);
      acc[t] = __builtin_amdgcn_mfma_f32_16x16x32_f16(a_lo[ks], b_hi[t][ks],
                                                      acc[t], 0, 0, 0);
    }
  }
  float* sb = s + (size_t)bh * SS * SS;
#pragma unroll
  for (int t = 0; t < 4; ++t) {
#pragma unroll
    for (int r = 0; r < 4; ++r) {
      float val = acc[t][r] * 0.125f;
      val = clampf(val, -15.0f, 15.0f);  // inputs finite: nan_to_num identity
      sb[(size_t)(i0 + wave * 16 + quad * 4 + r) * SS + j0 + t * 16 + l16] = val;
    }
  }
}

// ---------------------------------------------------------------------------
// K_rowstat: per-row fused ma + autopoietic transform (one wave per row).
__global__ __launch_bounds__(64) void k_rowstat(
    const float* __restrict__ s, const float* __restrict__ T,
    float* __restrict__ ma, float* __restrict__ t_un,
    float* __restrict__ rowred) {
  const int row = blockIdx.x;  // b*S + i
  const int b_ = row >> 9, i = row & 511;
  const int lane = threadIdx.x;

  float4 a0 = {0.f, 0.f, 0.f, 0.f}, a1 = {0.f, 0.f, 0.f, 0.f};
#pragma unroll
  for (int hh = 0; hh < NH; ++hh) {
    const float4* p = reinterpret_cast<const float4*>(
                          s + (((size_t)(b_ * NH + hh) * SS) + i) * SS) +
                      lane * 2;
    float4 u0 = p[0], u1 = p[1];
    a0.x += u0.x; a0.y += u0.y; a0.z += u0.z; a0.w += u0.w;
    a1.x += u1.x; a1.y += u1.y; a1.z += u1.z; a1.w += u1.w;
  }
  float m[8] = {a0.x * 0.125f, a0.y * 0.125f, a0.z * 0.125f, a0.w * 0.125f,
                a1.x * 0.125f, a1.y * 0.125f, a1.z * 0.125f, a1.w * 0.125f};
  {
    float4* mp = reinterpret_cast<float4*>(ma + ((size_t)b_ * SS + i) * SS) +
                 lane * 2;
    float4 w0 = {m[0], m[1], m[2], m[3]}, w1v = {m[4], m[5], m[6], m[7]};
    mp[0] = w0;
    mp[1] = w1v;
  }
  float sma = 0.f, sma2 = 0.f, mabs = 0.f;
#pragma unroll
  for (int e = 0; e < 8; ++e) {
    sma += m[e];
    sma2 += m[e] * m[e];
    mabs = fmaxf(mabs, fabsf(m[e]));
  }
  sma = waveRedSum(sma);
  sma2 = waveRedSum(sma2);
  mabs = waveRedMax(mabs);

  float ex[8], esum = 0.f;
#pragma unroll
  for (int e = 0; e < 8; ++e) {
    ex[e] = expf(clampf(m[e], -10.f, 10.f));
    esum += ex[e];
  }
  esum = waveRedSum(esum);
  float inv = 1.0f / esum;
  float Hv[8], sH = 0.f;
#pragma unroll
  for (int e = 0; e < 8; ++e) {
    float p = ex[e] * inv;
    Hv[e] = -p * logf(p + 1e-6f);
    sH += Hv[e];
  }
  sH = waveRedSum(sH);

  float fx[8], fsum = 0.f;
#pragma unroll
  for (int e = 0; e < 8; ++e) {
    fx[e] = expf(3.0f * Hv[e]);
    fsum += fx[e];
  }
  fsum = waveRedSum(fsum);
  float finv = 1.0f / fsum;

  float t[8], st = 0.f, st2 = 0.f;
#pragma unroll
  for (int e = 0; e < 8; ++e) {
    float sa = clampf(m[e], -8.f, 8.f) * 0.05f;
    float pos = (sa + 0.4f) * ((float)NTAB / 0.8f);
    int idx = (int)pos;
    idx = idx < 0 ? 0 : (idx > NTAB - 1 ? NTAB - 1 : idx);
    float frac = pos - (float)idx;
    float g0 = T[idx], g1 = T[idx + 1];
    float sig = g0 + (g1 - g0) * frac;
    t[e] = sig * fx[e] * finv;
    st += t[e];
    st2 += t[e] * t[e];
  }
  st = waveRedSum(st);
  st2 = waveRedSum(st2);
  {
    float4* tp = reinterpret_cast<float4*>(t_un + ((size_t)b_ * SS + i) * SS) +
                 lane * 2;
    float4 w0 = {t[0], t[1], t[2], t[3]}, w1v = {t[4], t[5], t[6], t[7]};
    tp[0] = w0;
    tp[1] = w1v;
  }
  if (lane == 0) {
    float* rp = rowred + (size_t)row * 8;
    rp[0] = sma; rp[1] = sma2; rp[2] = mabs;
    rp[3] = st;  rp[4] = st2;  rp[5] = sH;
  }
}

// ---------------------------------------------------------------------------
// K_consts: reduce per-row partials -> per-batch blend constants.
__global__ __launch_bounds__(256) void k_consts(
    const float* __restrict__ rowred, float* __restrict__ cst) {
  const int b_ = blockIdx.x;
  const int tid = threadIdx.x;
  __shared__ float red[4];
  const float* r0 = rowred + ((size_t)b_ * SS + tid * 2) * 8;
  const float* r1 = r0 + 8;
  float sma = blockRedSum(r0[0] + r1[0], red);
  float sma2 = blockRedSum(r0[1] + r1[1], red);
  float mabs = blockRedMax(fmaxf(r0[2], r1[2]), red);
  float st = blockRedSum(r0[3] + r1[3], red);
  float st2 = blockRedSum(r0[4] + r1[4], red);
  float sH = blockRedSum(r0[5] + r1[5], red);
  if (tid == 0) {
    const float N = (float)(SS * SS);
    float eo = sqrtf(sma2) + 1e-4f;
    float et = sqrtf(st2) + 1e-4f;
    float r = clampf(eo / et, 0.8f, 1.2f);
    float tmean = r * st / N;
    float om = sma / N;
    float vart = r * r * fmaxf(st2 / N - (st / N) * (st / N), 0.f);
    float tstd = sqrtf(fmaxf(vart, 0.01f));
    float varo = fmaxf(sma2 / N - om * om, 0.f);
    float ostd = sqrtf(fmaxf(varo, 0.01f));
    float gd = clampf(ostd / tstd, 0.8f, 1.2f);
    float ar = clampf(mabs, 1.f, 10.f);
    float sm = clampf(0.3f / log1pf(ar), 0.1f, 0.5f);
    float ent = sH / N;
    float ne = ent / logf((float)SS);
    float rr = 0.4f * (1.f - clampf(ne, 0.f, 0.4f));
    float G = sm * gd;
    cst[b_ * 4 + 0] = rr * (1.f - G) * tmean;  // c0
    cst[b_ * 4 + 1] = rr * G * r;              // c1 (multiplies t_un)
    cst[b_ * 4 + 2] = rr;                      // c2 (multiplies ma)
  }
}

// ---------------------------------------------------------------------------
// K_blend: blend + row softmax, in-place s -> attn. grid (512, 32), block 256.
__global__ __launch_bounds__(256) void k_blend(
    float* __restrict__ s, const float* __restrict__ ma,
    const float* __restrict__ t_un, const float* __restrict__ cst,
    const float* __restrict__ tau) {
  const int i = blockIdx.x;
  const int bh = blockIdx.y;
  const int b_ = bh >> 3;
  const int tid = threadIdx.x;
  __shared__ float red[4];
  const float c0 = cst[b_ * 4 + 0], c1 = cst[b_ * 4 + 1], c2 = cst[b_ * 4 + 2];
  const float itau = 1.0f / tau[0];
  float* srow = s + ((size_t)bh * SS + i) * SS;
  const float* mrow = ma + ((size_t)b_ * SS + i) * SS;
  const float* trow = t_un + ((size_t)b_ * SS + i) * SS;
  float v0 = (srow[tid] + c0 + c1 * trow[tid] - c2 * mrow[tid]) * itau;
  float v1 = (srow[tid + 256] + c0 + c1 * trow[tid + 256] - c2 * mrow[tid + 256]) * itau;
  float mx = blockRedMax(fmaxf(v0, v1), red);
  float e0 = expf(v0 - mx), e1 = expf(v1 - mx);
  float sum = blockRedSum(e0 + e1, red);
  float inv = 1.0f / sum;
  srow[tid] = e0 * inv;
  srow[tid + 256] = e1 * inv;
}

// ---------------------------------------------------------------------------
// K_av: out = attn @ v via 3-term f16 MFMA; attn fp32 converted in-register.
// A = s (attn) [bh][512][512] fp32, B = v_t hi/lo [bh][64][512].
// grid (8 mb, 32 bh), block 256 (4 waves stacked m, wave 16m x 64n).
__global__ __launch_bounds__(256) void k_av_mfma(
    const float* __restrict__ s, const _Float16* __restrict__ vth,
    const _Float16* __restrict__ vtl, _Float16* __restrict__ oh,
    _Float16* __restrict__ ol) {
  const int bh = blockIdx.y;
  const int b_ = bh >> 3, hh = bh & 7;
  const int tid = threadIdx.x;
  const int wave = tid >> 6, lane = tid & 63;
  const int quad = lane >> 4, l16 = lane & 15;
  const int m0 = blockIdx.x * 64 + wave * 16;
  const float* ab = s + (size_t)bh * SS * SS;

  f32x4 acc[4] = {};
  for (int k0 = 0; k0 < SS; k0 += 32) {
    const float* ap = ab + (size_t)(m0 + l16) * SS + k0 + quad * 8;
    float4 f0 = *(const float4*)ap;
    float4 f1 = *(const float4*)(ap + 4);
    float fv[8] = {f0.x, f0.y, f0.z, f0.w, f1.x, f1.y, f1.z, f1.w};
    f16x8 ah, al;
#pragma unroll
    for (int j = 0; j < 8; ++j) {
      HL r = split16(fv[j]);
      ah[j] = r.h;
      al[j] = r.l;
    }
#pragma unroll
    for (int nt = 0; nt < 4; ++nt) {
      const size_t boff = ((size_t)bh * HD + nt * 16 + l16) * SS + k0 + quad * 8;
      f16x8 bh_ = *(const f16x8*)(vth + boff);
      f16x8 bl_ = *(const f16x8*)(vtl + boff);
      acc[nt] = __builtin_amdgcn_mfma_f32_16x16x32_f16(ah, bh_, acc[nt], 0, 0, 0);
      acc[nt] = __builtin_amdgcn_mfma_f32_16x16x32_f16(ah, bl_, acc[nt], 0, 0, 0);
      acc[nt] = __builtin_amdgcn_mfma_f32_16x16x32_f16(al, bh_, acc[nt], 0, 0, 0);
    }
  }
#pragma unroll
  for (int nt = 0; nt < 4; ++nt) {
#pragma unroll
    for (int r = 0; r < 4; ++r) {
      const int si = m0 + quad * 4 + r;
      const size_t idx = ((size_t)(b_ * SS + si)) * EE + hh * HD + nt * 16 + l16;
      HL sp = split16(acc[nt][r]);
      oh[idx] = sp.h;
      ol[idx] = sp.l;
    }
  }
}

// ---------------------------------------------------------------------------
// K_out: out = o @ Wo + bo via 3-term f16 MFMA, fp32 output.
// grid (8 nb, 32 mb), block 256 (4 waves stacked m, wave 16m x 64n).
__global__ __launch_bounds__(256) void k_out_mfma(
    const _Float16* __restrict__ oh, const _Float16* __restrict__ ol,
    const _Float16* __restrict__ Wth, const _Float16* __restrict__ Wtl,
    const float* __restrict__ bo, float* __restrict__ out) {
  const int tid = threadIdx.x;
  const int wave = tid >> 6, lane = tid & 63;
  const int quad = lane >> 4, l16 = lane & 15;
  const int m0 = blockIdx.y * 64 + wave * 16;
  const int n0 = blockIdx.x * 64;
  const _Float16* Bh = Wth + (size_t)3 * EE * EE;  // Wo^T
  const _Float16* Bl = Wtl + (size_t)3 * EE * EE;

  f32x4 acc[4] = {};
  for (int k0 = 0; k0 < EE; k0 += 32) {
    const size_t aoff = (size_t)(m0 + l16) * EE + k0 + quad * 8;
    f16x8 ah = *(const f16x8*)(oh + aoff);
    f16x8 al = *(const f16x8*)(ol + aoff);
#pragma unroll
    for (int nt = 0; nt < 4; ++nt) {
      const size_t boff = (size_t)(n0 + nt * 16 + l16) * EE + k0 + quad * 8;
      f16x8 bh_ = *(const f16x8*)(Bh + boff);
      f16x8 bl_ = *(const f16x8*)(Bl + boff);
      acc[nt] = __builtin_amdgcn_mfma_f32_16x16x32_f16(ah, bh_, acc[nt], 0, 0, 0);
      acc[nt] = __builtin_amdgcn_mfma_f32_16x16x32_f16(ah, bl_, acc[nt], 0, 0, 0);
      acc[nt] = __builtin_amdgcn_mfma_f32_16x16x32_f16(al, bh_, acc[nt], 0, 0, 0);
    }
  }
#pragma unroll
  for (int nt = 0; nt < 4; ++nt) {
    const int col = n0 + nt * 16 + l16;
    const float bb = bo[col];
#pragma unroll
    for (int r = 0; r < 4; ++r) {
      const int m = m0 + quad * 4 + r;
      out[(size_t)m * EE + col] = acc[nt][r] + bb;
    }
  }
}

// ---------------------------------------------------------------------------
extern "C" void kernel_launch(void* const* d_in, const int* in_sizes, int n_in,
                              void* d_out, int out_size, void* d_ws,
                              size_t ws_size, hipStream_t stream) {
  const float* x = (const float*)d_in[0];
  const float* Wq = (const float*)d_in[1];
  const float* bq = (const float*)d_in[2];
  const float* Wk = (const float*)d_in[3];
  const float* bk = (const float*)d_in[4];
  const float* Wv = (const float*)d_in[5];
  const float* bv = (const float*)d_in[6];
  const float* Wo = (const float*)d_in[7];
  const float* bo = (const float*)d_in[8];
  const float* w1 = (const float*)d_in[9];
  const float* b1 = (const float*)d_in[10];
  const float* w2 = (const float*)d_in[11];
  const float* b2 = (const float*)d_in[12];
  const float* tau = (const float*)d_in[13];
  float* out = (float*)d_out;

  const size_t NX = (size_t)2048 * EE;   // 1M elems (x, o)
  const size_t NW = (size_t)4 * EE * EE; // 1M elems (4 W's)
  const size_t NQK = (size_t)BB * NH * SS * HD;  // 1M elems

  _Float16* xh = (_Float16*)d_ws;
  _Float16* xl = xh + NX;
  _Float16* Wth = xl + NX;
  _Float16* Wtl = Wth + NW;
  _Float16* qh = Wtl + NW;
  _Float16* ql = qh + NQK;
  _Float16* kh = ql + NQK;
  _Float16* kl = kh + NQK;
  float* v = (float*)(kl + NQK);
  _Float16* vth = (_Float16*)(v + NQK);
  _Float16* vtl = vth + NQK;
  float* s = (float*)(vtl + NQK);
  float* ma = s + (size_t)BB * NH * SS * SS;
  float* t_un = ma + (size_t)BB * SS * SS;
  float* T = t_un + (size_t)BB * SS * SS;
  float* rowred = T + 8192;
  float* cst = rowred + 2048 * 8;
  _Float16* oh = xh;  // alias: x dead after k_qkv_mfma
  _Float16* ol = xl;

  k_table<<<17, 256, 0, stream>>>(w1, b1, w2, b2, T);
  k_split_x<<<512, 256, 0, stream>>>(x, xh, xl);
  k_split_wt<<<dim3(8, 8, 4), 256, 0, stream>>>(Wq, Wk, Wv, Wo, Wth, Wtl);
  k_qkv_mfma<<<dim3(4, 32, 3), 256, 0, stream>>>(xh, xl, Wth, Wtl, bq, bk, bv,
                                                 qh, ql, kh, kl, v);
  k_scores_mfma<<<dim3(8, 8, 32), 256, 0, stream>>>(qh, ql, kh, kl, s);
  k_vt<<<dim3(8, 32), 256, 0, stream>>>(v, vth, vtl);
  k_rowstat<<<2048, 64, 0, stream>>>(s, T, ma, t_un, rowred);
  k_consts<<<4, 256, 0, stream>>>(rowred, cst);
  k_blend<<<dim3(512, 32), 256, 0, stream>>>(s, ma, t_un, cst, tau);
  k_av_mfma<<<dim3(8, 32), 256, 0, stream>>>(s, vth, vtl, oh, ol);
  k_out_mfma<<<dim3(8, 32), 256, 0, stream>>>(oh, ol, Wth, Wtl, bo, out);
}

// Round 5
// 248.632 us; speedup vs baseline: 1.8974x; 1.0304x over previous
//
#include <hip/hip_runtime.h>
#include <math.h>

// Problem constants (fixed by setup_inputs)
#define BB 4
#define SS 512
#define EE 512
#define NH 8
#define HD 64
#define NC 128
#define NTAB 4096  // table intervals over sa in [-0.4, 0.4]

typedef _Float16 f16x8 __attribute__((ext_vector_type(8)));
typedef float f32x4 __attribute__((ext_vector_type(4)));

struct HL { _Float16 h, l; };

__device__ __forceinline__ float clampf(float v, float lo, float hi) {
  return fminf(fmaxf(v, lo), hi);
}
__device__ __forceinline__ HL split16(float x) {
  HL r;
  r.h = (_Float16)x;
  r.l = (_Float16)(x - (float)r.h);
  return r;
}

__device__ __forceinline__ float waveRedSum(float v) {
#pragma unroll
  for (int o = 32; o; o >>= 1) v += __shfl_xor(v, o);
  return v;
}
__device__ __forceinline__ float waveRedMax(float v) {
#pragma unroll
  for (int o = 32; o; o >>= 1) v = fmaxf(v, __shfl_xor(v, o));
  return v;
}
// blockDim.x == 256 (4 waves) assumed
__device__ __forceinline__ float blockRedSum(float v, float* red) {
  int tid = threadIdx.x;
  v = waveRedSum(v);
  __syncthreads();
  if ((tid & 63) == 0) red[tid >> 6] = v;
  __syncthreads();
  return red[0] + red[1] + red[2] + red[3];
}
__device__ __forceinline__ float blockRedMax(float v, float* red) {
  int tid = threadIdx.x;
  v = waveRedMax(v);
  __syncthreads();
  if ((tid & 63) == 0) red[tid >> 6] = v;
  __syncthreads();
  return fmaxf(fmaxf(red[0], red[1]), fmaxf(red[2], red[3]));
}

// ---------------------------------------------------------------------------
// K_prep: fused preprocessing (all independent):
//   blocks [0,17): sigmoid table
//   blocks [17,529): split x -> f16 hi/lo
//   blocks [529,785): transpose+split the 4 weight matrices
__global__ __launch_bounds__(256) void k_prep(
    const float* __restrict__ w1, const float* __restrict__ b1,
    const float* __restrict__ w2, const float* __restrict__ b2,
    float* __restrict__ T, const float* __restrict__ x,
    _Float16* __restrict__ xh, _Float16* __restrict__ xl,
    const float* __restrict__ Wq, const float* __restrict__ Wk,
    const float* __restrict__ Wv, const float* __restrict__ Wo,
    _Float16* __restrict__ Wth, _Float16* __restrict__ Wtl) {
  const int bid = blockIdx.x;
  const int tid = threadIdx.x;
  if (bid < 17) {
    int idx = bid * 256 + tid;
    if (idx > NTAB) return;
    float sa = -0.4f + (float)idx * (0.8f / (float)NTAB);
    float ap = 0.f;
#pragma unroll 4
    for (int c = 0; c < NC; ++c) {
      float h = fminf(fmaxf(sa * w1[c] + b1[c], 0.f), 5.f);
      ap += h * w2[c];
    }
    ap = clampf(ap + b2[0], -5.f, 5.f);
    float tay = clampf(1.0f + 0.05f * (ap * 50.0f), 0.5f, 1.5f);
    T[idx] = 1.0f / (1.0f + expf(-tay));
  } else if (bid < 529) {
    int idx = ((bid - 17) * 256 + tid) * 8;
    float4 u0 = *(const float4*)(x + idx);
    float4 u1 = *(const float4*)(x + idx + 4);
    float f[8] = {u0.x, u0.y, u0.z, u0.w, u1.x, u1.y, u1.z, u1.w};
    f16x8 h, l;
#pragma unroll
    for (int j = 0; j < 8; ++j) {
      HL r = split16(f[j]);
      h[j] = r.h;
      l[j] = r.l;
    }
    *(f16x8*)(xh + idx) = h;
    *(f16x8*)(xl + idx) = l;
  } else {
    const int j = bid - 529;          // [0,256)
    const int z = j >> 6;             // matrix
    const int rem = j & 63;
    const int k0 = (rem & 7) * 64, n0 = (rem >> 3) * 64;
    const float* W = (z == 0) ? Wq : (z == 1) ? Wk : (z == 2) ? Wv : Wo;
    __shared__ float Tt[64][68];
    const int r = tid >> 2, c = (tid & 3) * 16;
#pragma unroll
    for (int jj = 0; jj < 16; jj += 4)
      *(float4*)&Tt[r][c + jj] =
          *(const float4*)(W + (size_t)(k0 + r) * EE + n0 + c + jj);
    __syncthreads();
    f16x8 h0, l0, h1, l1;
#pragma unroll
    for (int jj = 0; jj < 8; ++jj) {
      HL r0 = split16(Tt[c + jj][r]);
      HL r1 = split16(Tt[c + 8 + jj][r]);
      h0[jj] = r0.h; l0[jj] = r0.l;
      h1[jj] = r1.h; l1[jj] = r1.l;
    }
    _Float16* dh = Wth + ((size_t)z * EE + n0 + r) * EE + k0 + c;
    _Float16* dl = Wtl + ((size_t)z * EE + n0 + r) * EE + k0 + c;
    *(f16x8*)dh = h0;
    *(f16x8*)(dh + 8) = h1;
    *(f16x8*)dl = l0;
    *(f16x8*)(dl + 8) = l1;
  }
}

// ---------------------------------------------------------------------------
// K_vt: v fp32 [bh][si][64] -> v_t hi/lo f16 [bh][64][si]. grid (8 si-tile, 32 bh).
__global__ __launch_bounds__(256) void k_vt(const float* __restrict__ v,
                                            _Float16* __restrict__ vth,
                                            _Float16* __restrict__ vtl) {
  const int bh = blockIdx.y;
  const int si0 = blockIdx.x * 64;
  __shared__ float T[64][68];
  const int tid = threadIdx.x;
  const int r = tid >> 2, c = (tid & 3) * 16;
#pragma unroll
  for (int j = 0; j < 16; j += 4)
    *(float4*)&T[r][c + j] =
        *(const float4*)(v + ((size_t)bh * SS + si0 + r) * HD + c + j);
  __syncthreads();
  f16x8 h0, l0, h1, l1;
#pragma unroll
  for (int j = 0; j < 8; ++j) {
    HL r0 = split16(T[c + j][r]);
    HL r1 = split16(T[c + 8 + j][r]);
    h0[j] = r0.h; l0[j] = r0.l;
    h1[j] = r1.h; l1[j] = r1.l;
  }
  _Float16* dh = vth + ((size_t)bh * HD + r) * SS + si0 + c;
  _Float16* dl = vtl + ((size_t)bh * HD + r) * SS + si0 + c;
  *(f16x8*)dh = h0;
  *(f16x8*)(dh + 8) = h1;
  *(f16x8*)dl = l0;
  *(f16x8*)(dl + 8) = l1;
}

// ---------------------------------------------------------------------------
// K_qkv: MFMA 3-term f16 GEMM. Block = 64m x 64n, 4 waves stacked in m
// (wave = 16m x 64n). grid (8 nb, 32 mb, 3 which) = 768 blocks = 12 waves/CU.
// q is pre-scaled by 0.125 (folded attention scale).
__global__ __launch_bounds__(256) void k_qkv_mfma(
    const _Float16* __restrict__ xh, const _Float16* __restrict__ xl,
    const _Float16* __restrict__ Wth, const _Float16* __restrict__ Wtl,
    const float* __restrict__ bq, const float* __restrict__ bk,
    const float* __restrict__ bv,
    _Float16* __restrict__ qh, _Float16* __restrict__ ql,
    _Float16* __restrict__ kh, _Float16* __restrict__ kl,
    float* __restrict__ v) {
  const int which = blockIdx.z;
  const int tid = threadIdx.x;
  const int wave = tid >> 6, lane = tid & 63;
  const int quad = lane >> 4, l16 = lane & 15;
  const int m0 = blockIdx.y * 64 + wave * 16;
  const int n0 = blockIdx.x * 64;
  const _Float16* Bh = Wth + (size_t)which * EE * EE;
  const _Float16* Bl = Wtl + (size_t)which * EE * EE;

  f32x4 acc[4] = {};
  for (int k0 = 0; k0 < EE; k0 += 32) {
    const size_t aoff = (size_t)(m0 + l16) * EE + k0 + quad * 8;
    f16x8 ah = *(const f16x8*)(xh + aoff);
    f16x8 al = *(const f16x8*)(xl + aoff);
#pragma unroll
    for (int nt = 0; nt < 4; ++nt) {
      const size_t off = (size_t)(n0 + nt * 16 + l16) * EE + k0 + quad * 8;
      f16x8 bhf = *(const f16x8*)(Bh + off);
      f16x8 blf = *(const f16x8*)(Bl + off);
      acc[nt] = __builtin_amdgcn_mfma_f32_16x16x32_f16(ah, bhf, acc[nt], 0, 0, 0);
      acc[nt] = __builtin_amdgcn_mfma_f32_16x16x32_f16(ah, blf, acc[nt], 0, 0, 0);
      acc[nt] = __builtin_amdgcn_mfma_f32_16x16x32_f16(al, bhf, acc[nt], 0, 0, 0);
    }
  }
  const float* bias = (which == 0) ? bq : (which == 1) ? bk : bv;
  const float postscale = (which == 0) ? 0.125f : 1.0f;
  const int mbase = m0 + quad * 4;
#pragma unroll
  for (int nt = 0; nt < 4; ++nt) {
    const int col = n0 + nt * 16 + l16;
    const float bb = bias[col];
    const int hh = col >> 6, d = col & 63;
#pragma unroll
    for (int r = 0; r < 4; ++r) {
      const int mm = mbase + r;
      const int b_ = mm >> 9, si = mm & 511;
      const size_t idx = (((size_t)(b_ * NH + hh)) * SS + si) * HD + d;
      const float val = (acc[nt][r] + bb) * postscale;
      if (which == 2) {
        v[idx] = val;
      } else {
        HL sp = split16(val);
        (which ? kh : qh)[idx] = sp.h;
        (which ? kl : ql)[idx] = sp.l;
      }
    }
  }
}

// ---------------------------------------------------------------------------
// K_scores: s = clip(q.k^T, -15, 15) via 3-term f16 MFMA (q pre-scaled).
// grid (8 nTiles, 8 mTiles, 32 bh), block 256 (4 waves stacked in m).
__global__ __launch_bounds__(256) void k_scores_mfma(
    const _Float16* __restrict__ qh, const _Float16* __restrict__ ql,
    const _Float16* __restrict__ kh, const _Float16* __restrict__ kl,
    float* __restrict__ s) {
  const int bh = blockIdx.z;
  const int i0 = blockIdx.y * 64, j0 = blockIdx.x * 64;
  const int tid = threadIdx.x;
  const int wave = tid >> 6, lane = tid & 63;
  const int quad = lane >> 4, l16 = lane & 15;

  const size_t qoff = ((size_t)bh * SS + i0 + wave * 16 + l16) * HD + quad * 8;
  f16x8 a_hi[2], a_lo[2];
#pragma unroll
  for (int ks = 0; ks < 2; ++ks) {
    a_hi[ks] = *(const f16x8*)(qh + qoff + ks * 32);
    a_lo[ks] = *(const f16x8*)(ql + qoff + ks * 32);
  }
  f16x8 b_hi[4][2], b_lo[4][2];
#pragma unroll
  for (int t = 0; t < 4; ++t) {
    const size_t koff = ((size_t)bh * SS + j0 + t * 16 + l16) * HD + quad * 8;
#pragma unroll
    for (int ks = 0; ks < 2; ++ks) {
      b_hi[t][ks] = *(const f16x8*)(kh + koff + ks * 32);
      b_lo[t][ks] = *(const f16x8*)(kl + koff + ks * 32);
    }
  }
  f32x4 acc[4] = {};
#pragma unroll
  for (int ks = 0; ks < 2; ++ks) {
#pragma unroll
    for (int t = 0; t < 4; ++t) {
      acc[t] = __builtin_amdgcn_mfma_f32_16x16x32_f16(a_hi[ks], b_hi[t][ks],
                                                      acc[t], 0, 0, 0);
      acc[t] = __builtin_amdgcn_mfma_f32_16x16x32_f16(a_hi[ks], b_lo[t][ks],
                                                      acc[t], 0, 0, 0);
      acc[t] = __builtin_amdgcn_mfma_f32_16x16x32_f16(a_lo[ks], b_hi[t][ks],
                                                      acc[t], 0, 0, 0);
    }
  }
  float* sb = s + (size_t)bh * SS * SS;
#pragma unroll
  for (int t = 0; t < 4; ++t) {
#pragma unroll
    for (int r = 0; r < 4; ++r) {
      float val = clampf(acc[t][r], -15.0f, 15.0f);  // inputs finite
      sb[(size_t)(i0 + wave * 16 + quad * 4 + r) * SS + j0 + t * 16 + l16] = val;
    }
  }
}

// ---------------------------------------------------------------------------
// K_rowstat: per-row fused ma + autopoietic transform (one wave per row).
__global__ __launch_bounds__(64) void k_rowstat(
    const float* __restrict__ s, const float* __restrict__ T,
    float* __restrict__ ma, float* __restrict__ t_un,
    float* __restrict__ rowred) {
  const int row = blockIdx.x;  // b*S + i
  const int b_ = row >> 9, i = row & 511;
  const int lane = threadIdx.x;

  float4 a0 = {0.f, 0.f, 0.f, 0.f}, a1 = {0.f, 0.f, 0.f, 0.f};
#pragma unroll
  for (int hh = 0; hh < NH; ++hh) {
    const float4* p = reinterpret_cast<const float4*>(
                          s + (((size_t)(b_ * NH + hh) * SS) + i) * SS) +
                      lane * 2;
    float4 u0 = p[0], u1 = p[1];
    a0.x += u0.x; a0.y += u0.y; a0.z += u0.z; a0.w += u0.w;
    a1.x += u1.x; a1.y += u1.y; a1.z += u1.z; a1.w += u1.w;
  }
  float m[8] = {a0.x * 0.125f, a0.y * 0.125f, a0.z * 0.125f, a0.w * 0.125f,
                a1.x * 0.125f, a1.y * 0.125f, a1.z * 0.125f, a1.w * 0.125f};
  {
    float4* mp = reinterpret_cast<float4*>(ma + ((size_t)b_ * SS + i) * SS) +
                 lane * 2;
    float4 w0 = {m[0], m[1], m[2], m[3]}, w1v = {m[4], m[5], m[6], m[7]};
    mp[0] = w0;
    mp[1] = w1v;
  }
  float sma = 0.f, sma2 = 0.f, mabs = 0.f;
#pragma unroll
  for (int e = 0; e < 8; ++e) {
    sma += m[e];
    sma2 += m[e] * m[e];
    mabs = fmaxf(mabs, fabsf(m[e]));
  }
  sma = waveRedSum(sma);
  sma2 = waveRedSum(sma2);
  mabs = waveRedMax(mabs);

  float ex[8], esum = 0.f;
#pragma unroll
  for (int e = 0; e < 8; ++e) {
    ex[e] = expf(clampf(m[e], -10.f, 10.f));
    esum += ex[e];
  }
  esum = waveRedSum(esum);
  float inv = 1.0f / esum;
  float Hv[8], sH = 0.f;
#pragma unroll
  for (int e = 0; e < 8; ++e) {
    float p = ex[e] * inv;
    Hv[e] = -p * logf(p + 1e-6f);
    sH += Hv[e];
  }
  sH = waveRedSum(sH);

  float fx[8], fsum = 0.f;
#pragma unroll
  for (int e = 0; e < 8; ++e) {
    fx[e] = expf(3.0f * Hv[e]);
    fsum += fx[e];
  }
  fsum = waveRedSum(fsum);
  float finv = 1.0f / fsum;

  float t[8], st = 0.f, st2 = 0.f;
#pragma unroll
  for (int e = 0; e < 8; ++e) {
    float sa = clampf(m[e], -8.f, 8.f) * 0.05f;
    float pos = (sa + 0.4f) * ((float)NTAB / 0.8f);
    int idx = (int)pos;
    idx = idx < 0 ? 0 : (idx > NTAB - 1 ? NTAB - 1 : idx);
    float frac = pos - (float)idx;
    float g0 = T[idx], g1 = T[idx + 1];
    float sig = g0 + (g1 - g0) * frac;
    t[e] = sig * fx[e] * finv;
    st += t[e];
    st2 += t[e] * t[e];
  }
  st = waveRedSum(st);
  st2 = waveRedSum(st2);
  {
    float4* tp = reinterpret_cast<float4*>(t_un + ((size_t)b_ * SS + i) * SS) +
                 lane * 2;
    float4 w0 = {t[0], t[1], t[2], t[3]}, w1v = {t[4], t[5], t[6], t[7]};
    tp[0] = w0;
    tp[1] = w1v;
  }
  if (lane == 0) {
    float* rp = rowred + (size_t)row * 8;
    rp[0] = sma; rp[1] = sma2; rp[2] = mabs;
    rp[3] = st;  rp[4] = st2;  rp[5] = sH;
  }
}

// ---------------------------------------------------------------------------
// K_consts: reduce per-row partials -> per-batch blend constants.
__global__ __launch_bounds__(256) void k_consts(
    const float* __restrict__ rowred, float* __restrict__ cst) {
  const int b_ = blockIdx.x;
  const int tid = threadIdx.x;
  __shared__ float red[4];
  const float* r0 = rowred + ((size_t)b_ * SS + tid * 2) * 8;
  const float* r1 = r0 + 8;
  float sma = blockRedSum(r0[0] + r1[0], red);
  float sma2 = blockRedSum(r0[1] + r1[1], red);
  float mabs = blockRedMax(fmaxf(r0[2], r1[2]), red);
  float st = blockRedSum(r0[3] + r1[3], red);
  float st2 = blockRedSum(r0[4] + r1[4], red);
  float sH = blockRedSum(r0[5] + r1[5], red);
  if (tid == 0) {
    const float N = (float)(SS * SS);
    float eo = sqrtf(sma2) + 1e-4f;
    float et = sqrtf(st2) + 1e-4f;
    float r = clampf(eo / et, 0.8f, 1.2f);
    float tmean = r * st / N;
    float om = sma / N;
    float vart = r * r * fmaxf(st2 / N - (st / N) * (st / N), 0.f);
    float tstd = sqrtf(fmaxf(vart, 0.01f));
    float varo = fmaxf(sma2 / N - om * om, 0.f);
    float ostd = sqrtf(fmaxf(varo, 0.01f));
    float gd = clampf(ostd / tstd, 0.8f, 1.2f);
    float ar = clampf(mabs, 1.f, 10.f);
    float sm = clampf(0.3f / log1pf(ar), 0.1f, 0.5f);
    float ent = sH / N;
    float ne = ent / logf((float)SS);
    float rr = 0.4f * (1.f - clampf(ne, 0.f, 0.4f));
    float G = sm * gd;
    cst[b_ * 4 + 0] = rr * (1.f - G) * tmean;  // c0
    cst[b_ * 4 + 1] = rr * G * r;              // c1 (multiplies t_un)
    cst[b_ * 4 + 2] = rr;                      // c2 (multiplies ma)
  }
}

// ---------------------------------------------------------------------------
// K_blend: blend + row softmax, in-place s -> attn. One wave per (bh,i) row.
// No max-subtraction: |v| <= ~21 so exp stays in fp32 range. grid 16384x64.
__global__ __launch_bounds__(64) void k_blend(
    float* __restrict__ s, const float* __restrict__ ma,
    const float* __restrict__ t_un, const float* __restrict__ cst,
    const float* __restrict__ tau) {
  const int rid = blockIdx.x;          // bh*512 + i
  const int bh = rid >> 9, i = rid & 511;
  const int b_ = bh >> 3;
  const int lane = threadIdx.x;
  const float c0 = cst[b_ * 4 + 0], c1 = cst[b_ * 4 + 1], c2 = cst[b_ * 4 + 2];
  const float itau = 1.0f / tau[0];
  float* srow = s + ((size_t)bh * SS + i) * SS;
  const float* mrow = ma + ((size_t)b_ * SS + i) * SS;
  const float* trow = t_un + ((size_t)b_ * SS + i) * SS;

  float4 sv[2], mv[2], tv[2];
#pragma unroll
  for (int u = 0; u < 2; ++u) {
    sv[u] = ((const float4*)srow)[lane * 2 + u];
    mv[u] = ((const float4*)mrow)[lane * 2 + u];
    tv[u] = ((const float4*)trow)[lane * 2 + u];
  }
  float e[8], sum = 0.f;
#pragma unroll
  for (int u = 0; u < 2; ++u) {
    const float* sp = (const float*)&sv[u];
    const float* mp = (const float*)&mv[u];
    const float* tp = (const float*)&tv[u];
#pragma unroll
    for (int j = 0; j < 4; ++j) {
      float vv = (sp[j] + c0 + c1 * tp[j] - c2 * mp[j]) * itau;
      e[u * 4 + j] = expf(vv);
      sum += e[u * 4 + j];
    }
  }
  sum = waveRedSum(sum);
  float inv = 1.0f / sum;
#pragma unroll
  for (int u = 0; u < 2; ++u) {
    float4 w = {e[u * 4 + 0] * inv, e[u * 4 + 1] * inv, e[u * 4 + 2] * inv,
                e[u * 4 + 3] * inv};
    ((float4*)srow)[lane * 2 + u] = w;
  }
}

// ---------------------------------------------------------------------------
// K_av: out = attn @ v via 3-term f16 MFMA; attn fp32 converted in-register.
// Wave = 16m x 32n. grid (2 nh, 8 mb, 32 bh) = 512 blocks, 2048 waves.
__global__ __launch_bounds__(256) void k_av_mfma(
    const float* __restrict__ s, const _Float16* __restrict__ vth,
    const _Float16* __restrict__ vtl, _Float16* __restrict__ oh,
    _Float16* __restrict__ ol) {
  const int bh = blockIdx.z;
  const int b_ = bh >> 3, hh = bh & 7;
  const int nh = blockIdx.x;           // n half: cols nh*32..nh*32+31
  const int tid = threadIdx.x;
  const int wave = tid >> 6, lane = tid & 63;
  const int quad = lane >> 4, l16 = lane & 15;
  const int m0 = blockIdx.y * 64 + wave * 16;
  const float* ab = s + (size_t)bh * SS * SS;

  f32x4 acc[2] = {};
  for (int k0 = 0; k0 < SS; k0 += 32) {
    const float* ap = ab + (size_t)(m0 + l16) * SS + k0 + quad * 8;
    float4 f0 = *(const float4*)ap;
    float4 f1 = *(const float4*)(ap + 4);
    float fv[8] = {f0.x, f0.y, f0.z, f0.w, f1.x, f1.y, f1.z, f1.w};
    f16x8 ah, al;
#pragma unroll
    for (int j = 0; j < 8; ++j) {
      HL r = split16(fv[j]);
      ah[j] = r.h;
      al[j] = r.l;
    }
#pragma unroll
    for (int nt = 0; nt < 2; ++nt) {
      const size_t boff =
          ((size_t)bh * HD + nh * 32 + nt * 16 + l16) * SS + k0 + quad * 8;
      f16x8 bh_ = *(const f16x8*)(vth + boff);
      f16x8 bl_ = *(const f16x8*)(vtl + boff);
      acc[nt] = __builtin_amdgcn_mfma_f32_16x16x32_f16(ah, bh_, acc[nt], 0, 0, 0);
      acc[nt] = __builtin_amdgcn_mfma_f32_16x16x32_f16(ah, bl_, acc[nt], 0, 0, 0);
      acc[nt] = __builtin_amdgcn_mfma_f32_16x16x32_f16(al, bh_, acc[nt], 0, 0, 0);
    }
  }
#pragma unroll
  for (int nt = 0; nt < 2; ++nt) {
#pragma unroll
    for (int r = 0; r < 4; ++r) {
      const int si = m0 + quad * 4 + r;
      const size_t idx = ((size_t)(b_ * SS + si)) * EE + hh * HD + nh * 32 +
                         nt * 16 + l16;
      HL sp = split16(acc[nt][r]);
      oh[idx] = sp.h;
      ol[idx] = sp.l;
    }
  }
}

// ---------------------------------------------------------------------------
// K_out: out = o @ Wo + bo via 3-term f16 MFMA, fp32 output.
// Wave = 16m x 32n. grid (16 nb, 32 mb) = 512 blocks, 2048 waves.
__global__ __launch_bounds__(256) void k_out_mfma(
    const _Float16* __restrict__ oh, const _Float16* __restrict__ ol,
    const _Float16* __restrict__ Wth, const _Float16* __restrict__ Wtl,
    const float* __restrict__ bo, float* __restrict__ out) {
  const int tid = threadIdx.x;
  const int wave = tid >> 6, lane = tid & 63;
  const int quad = lane >> 4, l16 = lane & 15;
  const int m0 = blockIdx.y * 64 + wave * 16;
  const int n0 = blockIdx.x * 32;
  const _Float16* Bh = Wth + (size_t)3 * EE * EE;  // Wo^T
  const _Float16* Bl = Wtl + (size_t)3 * EE * EE;

  f32x4 acc[2] = {};
  for (int k0 = 0; k0 < EE; k0 += 32) {
    const size_t aoff = (size_t)(m0 + l16) * EE + k0 + quad * 8;
    f16x8 ah = *(const f16x8*)(oh + aoff);
    f16x8 al = *(const f16x8*)(ol + aoff);
#pragma unroll
    for (int nt = 0; nt < 2; ++nt) {
      const size_t boff = (size_t)(n0 + nt * 16 + l16) * EE + k0 + quad * 8;
      f16x8 bh_ = *(const f16x8*)(Bh + boff);
      f16x8 bl_ = *(const f16x8*)(Bl + boff);
      acc[nt] = __builtin_amdgcn_mfma_f32_16x16x32_f16(ah, bh_, acc[nt], 0, 0, 0);
      acc[nt] = __builtin_amdgcn_mfma_f32_16x16x32_f16(ah, bl_, acc[nt], 0, 0, 0);
      acc[nt] = __builtin_amdgcn_mfma_f32_16x16x32_f16(al, bh_, acc[nt], 0, 0, 0);
    }
  }
#pragma unroll
  for (int nt = 0; nt < 2; ++nt) {
    const int col = n0 + nt * 16 + l16;
    const float bb = bo[col];
#pragma unroll
    for (int r = 0; r < 4; ++r) {
      const int m = m0 + quad * 4 + r;
      out[(size_t)m * EE + col] = acc[nt][r] + bb;
    }
  }
}

// ---------------------------------------------------------------------------
extern "C" void kernel_launch(void* const* d_in, const int* in_sizes, int n_in,
                              void* d_out, int out_size, void* d_ws,
                              size_t ws_size, hipStream_t stream) {
  const float* x = (const float*)d_in[0];
  const float* Wq = (const float*)d_in[1];
  const float* bq = (const float*)d_in[2];
  const float* Wk = (const float*)d_in[3];
  const float* bk = (const float*)d_in[4];
  const float* Wv = (const float*)d_in[5];
  const float* bv = (const float*)d_in[6];
  const float* Wo = (const float*)d_in[7];
  const float* bo = (const float*)d_in[8];
  const float* w1 = (const float*)d_in[9];
  const float* b1 = (const float*)d_in[10];
  const float* w2 = (const float*)d_in[11];
  const float* b2 = (const float*)d_in[12];
  const float* tau = (const float*)d_in[13];
  float* out = (float*)d_out;

  const size_t NX = (size_t)2048 * EE;           // 1M elems (x, o)
  const size_t NW = (size_t)4 * EE * EE;         // 1M elems (4 W's)
  const size_t NQK = (size_t)BB * NH * SS * HD;  // 1M elems

  _Float16* xh = (_Float16*)d_ws;
  _Float16* xl = xh + NX;
  _Float16* Wth = xl + NX;
  _Float16* Wtl = Wth + NW;
  _Float16* qh = Wtl + NW;
  _Float16* ql = qh + NQK;
  _Float16* kh = ql + NQK;
  _Float16* kl = kh + NQK;
  float* v = (float*)(kl + NQK);
  _Float16* vth = (_Float16*)(v + NQK);
  _Float16* vtl = vth + NQK;
  float* s = (float*)(vtl + NQK);
  float* ma = s + (size_t)BB * NH * SS * SS;
  float* t_un = ma + (size_t)BB * SS * SS;
  float* T = t_un + (size_t)BB * SS * SS;
  float* rowred = T + 8192;
  float* cst = rowred + 2048 * 8;
  _Float16* oh = xh;  // alias: x dead after k_qkv_mfma
  _Float16* ol = xl;

  k_prep<<<785, 256, 0, stream>>>(w1, b1, w2, b2, T, x, xh, xl, Wq, Wk, Wv, Wo,
                                  Wth, Wtl);
  k_qkv_mfma<<<dim3(8, 32, 3), 256, 0, stream>>>(xh, xl, Wth, Wtl, bq, bk, bv,
                                                 qh, ql, kh, kl, v);
  k_scores_mfma<<<dim3(8, 8, 32), 256, 0, stream>>>(qh, ql, kh, kl, s);
  k_vt<<<dim3(8, 32), 256, 0, stream>>>(v, vth, vtl);
  k_rowstat<<<2048, 64, 0, stream>>>(s, T, ma, t_un, rowred);
  k_consts<<<4, 256, 0, stream>>>(rowred, cst);
  k_blend<<<16384, 64, 0, stream>>>(s, ma, t_un, cst, tau);
  k_av_mfma<<<dim3(2, 8, 32), 256, 0, stream>>>(s, vth, vtl, oh, ol);
  k_out_mfma<<<dim3(16, 32), 256, 0, stream>>>(oh, ol, Wth, Wtl, bo, out);
}

// Round 6
// 198.398 us; speedup vs baseline: 2.3779x; 1.2532x over previous
//
#include <hip/hip_runtime.h>
#include <math.h>

// Problem constants (fixed by setup_inputs)
#define BB 4
#define SS 512
#define EE 512
#define NH 8
#define HD 64
#define NC 128
#define NTAB 4096  // table intervals over sa in [-0.4, 0.4]

typedef _Float16 f16x8 __attribute__((ext_vector_type(8)));
typedef float f32x4 __attribute__((ext_vector_type(4)));

struct HL { _Float16 h, l; };

__device__ __forceinline__ float clampf(float v, float lo, float hi) {
  return fminf(fmaxf(v, lo), hi);
}
__device__ __forceinline__ HL split16(float x) {
  HL r;
  r.h = (_Float16)x;
  r.l = (_Float16)(x - (float)r.h);
  return r;
}

__device__ __forceinline__ float waveRedSum(float v) {
#pragma unroll
  for (int o = 32; o; o >>= 1) v += __shfl_xor(v, o);
  return v;
}
__device__ __forceinline__ float waveRedMax(float v) {
#pragma unroll
  for (int o = 32; o; o >>= 1) v = fmaxf(v, __shfl_xor(v, o));
  return v;
}
// blockDim.x == 256 (4 waves) assumed
__device__ __forceinline__ float blockRedSum(float v, float* red) {
  int tid = threadIdx.x;
  v = waveRedSum(v);
  __syncthreads();
  if ((tid & 63) == 0) red[tid >> 6] = v;
  __syncthreads();
  return red[0] + red[1] + red[2] + red[3];
}
__device__ __forceinline__ float blockRedMax(float v, float* red) {
  int tid = threadIdx.x;
  v = waveRedMax(v);
  __syncthreads();
  if ((tid & 63) == 0) red[tid >> 6] = v;
  __syncthreads();
  return fmaxf(fmaxf(red[0], red[1]), fmaxf(red[2], red[3]));
}

// ---------------------------------------------------------------------------
// K_prep: fused preprocessing (all independent):
//   blocks [0,17): sigmoid table
//   blocks [17,529): split x -> f16 hi/lo
//   blocks [529,785): transpose+split the 4 weight matrices
__global__ __launch_bounds__(256) void k_prep(
    const float* __restrict__ w1, const float* __restrict__ b1,
    const float* __restrict__ w2, const float* __restrict__ b2,
    float* __restrict__ T, const float* __restrict__ x,
    _Float16* __restrict__ xh, _Float16* __restrict__ xl,
    const float* __restrict__ Wq, const float* __restrict__ Wk,
    const float* __restrict__ Wv, const float* __restrict__ Wo,
    _Float16* __restrict__ Wth, _Float16* __restrict__ Wtl) {
  const int bid = blockIdx.x;
  const int tid = threadIdx.x;
  if (bid < 17) {
    int idx = bid * 256 + tid;
    if (idx > NTAB) return;
    float sa = -0.4f + (float)idx * (0.8f / (float)NTAB);
    float ap = 0.f;
#pragma unroll 4
    for (int c = 0; c < NC; ++c) {
      float h = fminf(fmaxf(sa * w1[c] + b1[c], 0.f), 5.f);
      ap += h * w2[c];
    }
    ap = clampf(ap + b2[0], -5.f, 5.f);
    float tay = clampf(1.0f + 0.05f * (ap * 50.0f), 0.5f, 1.5f);
    T[idx] = 1.0f / (1.0f + expf(-tay));
  } else if (bid < 529) {
    int idx = ((bid - 17) * 256 + tid) * 8;
    float4 u0 = *(const float4*)(x + idx);
    float4 u1 = *(const float4*)(x + idx + 4);
    float f[8] = {u0.x, u0.y, u0.z, u0.w, u1.x, u1.y, u1.z, u1.w};
    f16x8 h, l;
#pragma unroll
    for (int j = 0; j < 8; ++j) {
      HL r = split16(f[j]);
      h[j] = r.h;
      l[j] = r.l;
    }
    *(f16x8*)(xh + idx) = h;
    *(f16x8*)(xl + idx) = l;
  } else {
    const int j = bid - 529;          // [0,256)
    const int z = j >> 6;             // matrix
    const int rem = j & 63;
    const int k0 = (rem & 7) * 64, n0 = (rem >> 3) * 64;
    const float* W = (z == 0) ? Wq : (z == 1) ? Wk : (z == 2) ? Wv : Wo;
    __shared__ float Tt[64][68];
    const int r = tid >> 2, c = (tid & 3) * 16;
#pragma unroll
    for (int jj = 0; jj < 16; jj += 4)
      *(float4*)&Tt[r][c + jj] =
          *(const float4*)(W + (size_t)(k0 + r) * EE + n0 + c + jj);
    __syncthreads();
    f16x8 h0, l0, h1, l1;
#pragma unroll
    for (int jj = 0; jj < 8; ++jj) {
      HL r0 = split16(Tt[c + jj][r]);
      HL r1 = split16(Tt[c + 8 + jj][r]);
      h0[jj] = r0.h; l0[jj] = r0.l;
      h1[jj] = r1.h; l1[jj] = r1.l;
    }
    _Float16* dh = Wth + ((size_t)z * EE + n0 + r) * EE + k0 + c;
    _Float16* dl = Wtl + ((size_t)z * EE + n0 + r) * EE + k0 + c;
    *(f16x8*)dh = h0;
    *(f16x8*)(dh + 8) = h1;
    *(f16x8*)dl = l0;
    *(f16x8*)(dl + 8) = l1;
  }
}

// ---------------------------------------------------------------------------
// K_vt: v fp32 [bh][si][64] -> v_t hi/lo f16 [bh][64][si]. grid (8 si-tile, 32 bh).
__global__ __launch_bounds__(256) void k_vt(const float* __restrict__ v,
                                            _Float16* __restrict__ vth,
                                            _Float16* __restrict__ vtl) {
  const int bh = blockIdx.y;
  const int si0 = blockIdx.x * 64;
  __shared__ float T[64][68];
  const int tid = threadIdx.x;
  const int r = tid >> 2, c = (tid & 3) * 16;
#pragma unroll
  for (int j = 0; j < 16; j += 4)
    *(float4*)&T[r][c + j] =
        *(const float4*)(v + ((size_t)bh * SS + si0 + r) * HD + c + j);
  __syncthreads();
  f16x8 h0, l0, h1, l1;
#pragma unroll
  for (int j = 0; j < 8; ++j) {
    HL r0 = split16(T[c + j][r]);
    HL r1 = split16(T[c + 8 + j][r]);
    h0[j] = r0.h; l0[j] = r0.l;
    h1[j] = r1.h; l1[j] = r1.l;
  }
  _Float16* dh = vth + ((size_t)bh * HD + r) * SS + si0 + c;
  _Float16* dl = vtl + ((size_t)bh * HD + r) * SS + si0 + c;
  *(f16x8*)dh = h0;
  *(f16x8*)(dh + 8) = h1;
  *(f16x8*)dl = l0;
  *(f16x8*)(dl + 8) = l1;
}

// ---------------------------------------------------------------------------
// K_qkv: LDS-staged 3-term f16 MFMA GEMM. Block = 64m x 64n, 4 waves stacked
// in m (wave = 16m x 64n). K staged 64/iter into LDS [64][72] (pad +8 keeps
// 16B alignment, <=2-way write conflicts). grid (8 nb, 32 mb, 3 which).
// q is pre-scaled by 0.125 (folded attention scale).
__global__ __launch_bounds__(256) void k_qkv_mfma(
    const _Float16* __restrict__ xh, const _Float16* __restrict__ xl,
    const _Float16* __restrict__ Wth, const _Float16* __restrict__ Wtl,
    const float* __restrict__ bq, const float* __restrict__ bk,
    const float* __restrict__ bv,
    _Float16* __restrict__ qh, _Float16* __restrict__ ql,
    _Float16* __restrict__ kh, _Float16* __restrict__ kl,
    float* __restrict__ v) {
  const int which = blockIdx.z;
  const int tid = threadIdx.x;
  const int wave = tid >> 6, lane = tid & 63;
  const int quad = lane >> 4, l16 = lane & 15;
  const int m0 = blockIdx.y * 64;
  const int n0 = blockIdx.x * 64;
  const _Float16* Bh = Wth + (size_t)which * EE * EE;
  const _Float16* Bl = Wtl + (size_t)which * EE * EE;

  __shared__ _Float16 LAh[64][72], LAl[64][72], LBh[64][72], LBl[64][72];

  const int sr0 = tid >> 3, sc0 = (tid & 7) * 8;          // chunk tid
  const int sr1 = (tid + 256) >> 3, sc1 = sc0;            // chunk tid+256

  f32x4 acc[4] = {};
  for (int k0 = 0; k0 < EE; k0 += 64) {
    if (k0) __syncthreads();  // previous-stage reads done before overwrite
    *(f16x8*)&LAh[sr0][sc0] = *(const f16x8*)(xh + (size_t)(m0 + sr0) * EE + k0 + sc0);
    *(f16x8*)&LAl[sr0][sc0] = *(const f16x8*)(xl + (size_t)(m0 + sr0) * EE + k0 + sc0);
    *(f16x8*)&LBh[sr0][sc0] = *(const f16x8*)(Bh + (size_t)(n0 + sr0) * EE + k0 + sc0);
    *(f16x8*)&LBl[sr0][sc0] = *(const f16x8*)(Bl + (size_t)(n0 + sr0) * EE + k0 + sc0);
    *(f16x8*)&LAh[sr1][sc1] = *(const f16x8*)(xh + (size_t)(m0 + sr1) * EE + k0 + sc1);
    *(f16x8*)&LAl[sr1][sc1] = *(const f16x8*)(xl + (size_t)(m0 + sr1) * EE + k0 + sc1);
    *(f16x8*)&LBh[sr1][sc1] = *(const f16x8*)(Bh + (size_t)(n0 + sr1) * EE + k0 + sc1);
    *(f16x8*)&LBl[sr1][sc1] = *(const f16x8*)(Bl + (size_t)(n0 + sr1) * EE + k0 + sc1);
    __syncthreads();
#pragma unroll
    for (int kk = 0; kk < 64; kk += 32) {
      f16x8 ah = *(const f16x8*)&LAh[wave * 16 + l16][kk + quad * 8];
      f16x8 al = *(const f16x8*)&LAl[wave * 16 + l16][kk + quad * 8];
#pragma unroll
      for (int nt = 0; nt < 4; ++nt) {
        f16x8 bhf = *(const f16x8*)&LBh[nt * 16 + l16][kk + quad * 8];
        f16x8 blf = *(const f16x8*)&LBl[nt * 16 + l16][kk + quad * 8];
        acc[nt] = __builtin_amdgcn_mfma_f32_16x16x32_f16(ah, bhf, acc[nt], 0, 0, 0);
        acc[nt] = __builtin_amdgcn_mfma_f32_16x16x32_f16(ah, blf, acc[nt], 0, 0, 0);
        acc[nt] = __builtin_amdgcn_mfma_f32_16x16x32_f16(al, bhf, acc[nt], 0, 0, 0);
      }
    }
  }
  const float* bias = (which == 0) ? bq : (which == 1) ? bk : bv;
  const float postscale = (which == 0) ? 0.125f : 1.0f;
  const int mbase = m0 + wave * 16 + quad * 4;
#pragma unroll
  for (int nt = 0; nt < 4; ++nt) {
    const int col = n0 + nt * 16 + l16;
    const float bb = bias[col];
    const int hh = col >> 6, d = col & 63;
#pragma unroll
    for (int r = 0; r < 4; ++r) {
      const int mm = mbase + r;
      const int b_ = mm >> 9, si = mm & 511;
      const size_t idx = (((size_t)(b_ * NH + hh)) * SS + si) * HD + d;
      const float val = (acc[nt][r] + bb) * postscale;
      if (which == 2) {
        v[idx] = val;
      } else {
        HL sp = split16(val);
        (which ? kh : qh)[idx] = sp.h;
        (which ? kl : ql)[idx] = sp.l;
      }
    }
  }
}

// ---------------------------------------------------------------------------
// K_scores: s = clip(q.k^T, -15, 15) via 3-term f16 MFMA (q pre-scaled).
// grid (8 nTiles, 8 mTiles, 32 bh), block 256 (4 waves stacked in m).
__global__ __launch_bounds__(256) void k_scores_mfma(
    const _Float16* __restrict__ qh, const _Float16* __restrict__ ql,
    const _Float16* __restrict__ kh, const _Float16* __restrict__ kl,
    float* __restrict__ s) {
  const int bh = blockIdx.z;
  const int i0 = blockIdx.y * 64, j0 = blockIdx.x * 64;
  const int tid = threadIdx.x;
  const int wave = tid >> 6, lane = tid & 63;
  const int quad = lane >> 4, l16 = lane & 15;

  const size_t qoff = ((size_t)bh * SS + i0 + wave * 16 + l16) * HD + quad * 8;
  f16x8 a_hi[2], a_lo[2];
#pragma unroll
  for (int ks = 0; ks < 2; ++ks) {
    a_hi[ks] = *(const f16x8*)(qh + qoff + ks * 32);
    a_lo[ks] = *(const f16x8*)(ql + qoff + ks * 32);
  }
  f16x8 b_hi[4][2], b_lo[4][2];
#pragma unroll
  for (int t = 0; t < 4; ++t) {
    const size_t koff = ((size_t)bh * SS + j0 + t * 16 + l16) * HD + quad * 8;
#pragma unroll
    for (int ks = 0; ks < 2; ++ks) {
      b_hi[t][ks] = *(const f16x8*)(kh + koff + ks * 32);
      b_lo[t][ks] = *(const f16x8*)(kl + koff + ks * 32);
    }
  }
  f32x4 acc[4] = {};
#pragma unroll
  for (int ks = 0; ks < 2; ++ks) {
#pragma unroll
    for (int t = 0; t < 4; ++t) {
      acc[t] = __builtin_amdgcn_mfma_f32_16x16x32_f16(a_hi[ks], b_hi[t][ks],
                                                      acc[t], 0, 0, 0);
      acc[t] = __builtin_amdgcn_mfma_f32_16x16x32_f16(a_hi[ks], b_lo[t][ks],
                                                      acc[t], 0, 0, 0);
      acc[t] = __builtin_amdgcn_mfma_f32_16x16x32_f16(a_lo[ks], b_hi[t][ks],
                                                      acc[t], 0, 0, 0);
    }
  }
  float* sb = s + (size_t)bh * SS * SS;
#pragma unroll
  for (int t = 0; t < 4; ++t) {
#pragma unroll
    for (int r = 0; r < 4; ++r) {
      float val = clampf(acc[t][r], -15.0f, 15.0f);  // inputs finite
      sb[(size_t)(i0 + wave * 16 + quad * 4 + r) * SS + j0 + t * 16 + l16] = val;
    }
  }
}

// ---------------------------------------------------------------------------
// K_rowstat: per-row fused ma + autopoietic transform (one wave per row).
__global__ __launch_bounds__(64) void k_rowstat(
    const float* __restrict__ s, const float* __restrict__ T,
    float* __restrict__ ma, float* __restrict__ t_un,
    float* __restrict__ rowred) {
  const int row = blockIdx.x;  // b*S + i
  const int b_ = row >> 9, i = row & 511;
  const int lane = threadIdx.x;

  float4 a0 = {0.f, 0.f, 0.f, 0.f}, a1 = {0.f, 0.f, 0.f, 0.f};
#pragma unroll
  for (int hh = 0; hh < NH; ++hh) {
    const float4* p = reinterpret_cast<const float4*>(
                          s + (((size_t)(b_ * NH + hh) * SS) + i) * SS) +
                      lane * 2;
    float4 u0 = p[0], u1 = p[1];
    a0.x += u0.x; a0.y += u0.y; a0.z += u0.z; a0.w += u0.w;
    a1.x += u1.x; a1.y += u1.y; a1.z += u1.z; a1.w += u1.w;
  }
  float m[8] = {a0.x * 0.125f, a0.y * 0.125f, a0.z * 0.125f, a0.w * 0.125f,
                a1.x * 0.125f, a1.y * 0.125f, a1.z * 0.125f, a1.w * 0.125f};
  {
    float4* mp = reinterpret_cast<float4*>(ma + ((size_t)b_ * SS + i) * SS) +
                 lane * 2;
    float4 w0 = {m[0], m[1], m[2], m[3]}, w1v = {m[4], m[5], m[6], m[7]};
    mp[0] = w0;
    mp[1] = w1v;
  }
  float sma = 0.f, sma2 = 0.f, mabs = 0.f;
#pragma unroll
  for (int e = 0; e < 8; ++e) {
    sma += m[e];
    sma2 += m[e] * m[e];
    mabs = fmaxf(mabs, fabsf(m[e]));
  }
  sma = waveRedSum(sma);
  sma2 = waveRedSum(sma2);
  mabs = waveRedMax(mabs);

  float ex[8], esum = 0.f;
#pragma unroll
  for (int e = 0; e < 8; ++e) {
    ex[e] = expf(clampf(m[e], -10.f, 10.f));
    esum += ex[e];
  }
  esum = waveRedSum(esum);
  float inv = 1.0f / esum;
  float Hv[8], sH = 0.f;
#pragma unroll
  for (int e = 0; e < 8; ++e) {
    float p = ex[e] * inv;
    Hv[e] = -p * logf(p + 1e-6f);
    sH += Hv[e];
  }
  sH = waveRedSum(sH);

  float fx[8], fsum = 0.f;
#pragma unroll
  for (int e = 0; e < 8; ++e) {
    fx[e] = expf(3.0f * Hv[e]);
    fsum += fx[e];
  }
  fsum = waveRedSum(fsum);
  float finv = 1.0f / fsum;

  float t[8], st = 0.f, st2 = 0.f;
#pragma unroll
  for (int e = 0; e < 8; ++e) {
    float sa = clampf(m[e], -8.f, 8.f) * 0.05f;
    float pos = (sa + 0.4f) * ((float)NTAB / 0.8f);
    int idx = (int)pos;
    idx = idx < 0 ? 0 : (idx > NTAB - 1 ? NTAB - 1 : idx);
    float frac = pos - (float)idx;
    float g0 = T[idx], g1 = T[idx + 1];
    float sig = g0 + (g1 - g0) * frac;
    t[e] = sig * fx[e] * finv;
    st += t[e];
    st2 += t[e] * t[e];
  }
  st = waveRedSum(st);
  st2 = waveRedSum(st2);
  {
    float4* tp = reinterpret_cast<float4*>(t_un + ((size_t)b_ * SS + i) * SS) +
                 lane * 2;
    float4 w0 = {t[0], t[1], t[2], t[3]}, w1v = {t[4], t[5], t[6], t[7]};
    tp[0] = w0;
    tp[1] = w1v;
  }
  if (lane == 0) {
    float* rp = rowred + (size_t)row * 8;
    rp[0] = sma; rp[1] = sma2; rp[2] = mabs;
    rp[3] = st;  rp[4] = st2;  rp[5] = sH;
  }
}

// ---------------------------------------------------------------------------
// K_consts: reduce per-row partials -> per-batch blend constants.
__global__ __launch_bounds__(256) void k_consts(
    const float* __restrict__ rowred, float* __restrict__ cst) {
  const int b_ = blockIdx.x;
  const int tid = threadIdx.x;
  __shared__ float red[4];
  const float* r0 = rowred + ((size_t)b_ * SS + tid * 2) * 8;
  const float* r1 = r0 + 8;
  float sma = blockRedSum(r0[0] + r1[0], red);
  float sma2 = blockRedSum(r0[1] + r1[1], red);
  float mabs = blockRedMax(fmaxf(r0[2], r1[2]), red);
  float st = blockRedSum(r0[3] + r1[3], red);
  float st2 = blockRedSum(r0[4] + r1[4], red);
  float sH = blockRedSum(r0[5] + r1[5], red);
  if (tid == 0) {
    const float N = (float)(SS * SS);
    float eo = sqrtf(sma2) + 1e-4f;
    float et = sqrtf(st2) + 1e-4f;
    float r = clampf(eo / et, 0.8f, 1.2f);
    float tmean = r * st / N;
    float om = sma / N;
    float vart = r * r * fmaxf(st2 / N - (st / N) * (st / N), 0.f);
    float tstd = sqrtf(fmaxf(vart, 0.01f));
    float varo = fmaxf(sma2 / N - om * om, 0.f);
    float ostd = sqrtf(fmaxf(varo, 0.01f));
    float gd = clampf(ostd / tstd, 0.8f, 1.2f);
    float ar = clampf(mabs, 1.f, 10.f);
    float sm = clampf(0.3f / log1pf(ar), 0.1f, 0.5f);
    float ent = sH / N;
    float ne = ent / logf((float)SS);
    float rr = 0.4f * (1.f - clampf(ne, 0.f, 0.4f));
    float G = sm * gd;
    cst[b_ * 4 + 0] = rr * (1.f - G) * tmean;  // c0
    cst[b_ * 4 + 1] = rr * G * r;              // c1 (multiplies t_un)
    cst[b_ * 4 + 2] = rr;                      // c2 (multiplies ma)
  }
}

// ---------------------------------------------------------------------------
// K_blend: blend + row softmax, in-place s -> attn. One wave per (bh,i) row.
// No max-subtraction: |v| <= ~21 so exp stays in fp32 range. grid 16384x64.
__global__ __launch_bounds__(64) void k_blend(
    float* __restrict__ s, const float* __restrict__ ma,
    const float* __restrict__ t_un, const float* __restrict__ cst,
    const float* __restrict__ tau) {
  const int rid = blockIdx.x;          // bh*512 + i
  const int bh = rid >> 9, i = rid & 511;
  const int b_ = bh >> 3;
  const int lane = threadIdx.x;
  const float c0 = cst[b_ * 4 + 0], c1 = cst[b_ * 4 + 1], c2 = cst[b_ * 4 + 2];
  const float itau = 1.0f / tau[0];
  float* srow = s + ((size_t)bh * SS + i) * SS;
  const float* mrow = ma + ((size_t)b_ * SS + i) * SS;
  const float* trow = t_un + ((size_t)b_ * SS + i) * SS;

  float4 sv[2], mv[2], tv[2];
#pragma unroll
  for (int u = 0; u < 2; ++u) {
    sv[u] = ((const float4*)srow)[lane * 2 + u];
    mv[u] = ((const float4*)mrow)[lane * 2 + u];
    tv[u] = ((const float4*)trow)[lane * 2 + u];
  }
  float e[8], sum = 0.f;
#pragma unroll
  for (int u = 0; u < 2; ++u) {
    const float* sp = (const float*)&sv[u];
    const float* mp = (const float*)&mv[u];
    const float* tp = (const float*)&tv[u];
#pragma unroll
    for (int j = 0; j < 4; ++j) {
      float vv = (sp[j] + c0 + c1 * tp[j] - c2 * mp[j]) * itau;
      e[u * 4 + j] = expf(vv);
      sum += e[u * 4 + j];
    }
  }
  sum = waveRedSum(sum);
  float inv = 1.0f / sum;
#pragma unroll
  for (int u = 0; u < 2; ++u) {
    float4 w = {e[u * 4 + 0] * inv, e[u * 4 + 1] * inv, e[u * 4 + 2] * inv,
                e[u * 4 + 3] * inv};
    ((float4*)srow)[lane * 2 + u] = w;
  }
}

// ---------------------------------------------------------------------------
// K_av: out = attn @ v via 3-term f16 MFMA; attn fp32 converted in-register.
// Wave = 16m x 32n. grid (2 nh, 8 mb, 32 bh) = 512 blocks, 2048 waves.
__global__ __launch_bounds__(256) void k_av_mfma(
    const float* __restrict__ s, const _Float16* __restrict__ vth,
    const _Float16* __restrict__ vtl, _Float16* __restrict__ oh,
    _Float16* __restrict__ ol) {
  const int bh = blockIdx.z;
  const int b_ = bh >> 3, hh = bh & 7;
  const int nh = blockIdx.x;           // n half: cols nh*32..nh*32+31
  const int tid = threadIdx.x;
  const int wave = tid >> 6, lane = tid & 63;
  const int quad = lane >> 4, l16 = lane & 15;
  const int m0 = blockIdx.y * 64 + wave * 16;
  const float* ab = s + (size_t)bh * SS * SS;

  f32x4 acc[2] = {};
  for (int k0 = 0; k0 < SS; k0 += 32) {
    const float* ap = ab + (size_t)(m0 + l16) * SS + k0 + quad * 8;
    float4 f0 = *(const float4*)ap;
    float4 f1 = *(const float4*)(ap + 4);
    float fv[8] = {f0.x, f0.y, f0.z, f0.w, f1.x, f1.y, f1.z, f1.w};
    f16x8 ah, al;
#pragma unroll
    for (int j = 0; j < 8; ++j) {
      HL r = split16(fv[j]);
      ah[j] = r.h;
      al[j] = r.l;
    }
#pragma unroll
    for (int nt = 0; nt < 2; ++nt) {
      const size_t boff =
          ((size_t)bh * HD + nh * 32 + nt * 16 + l16) * SS + k0 + quad * 8;
      f16x8 bh_ = *(const f16x8*)(vth + boff);
      f16x8 bl_ = *(const f16x8*)(vtl + boff);
      acc[nt] = __builtin_amdgcn_mfma_f32_16x16x32_f16(ah, bh_, acc[nt], 0, 0, 0);
      acc[nt] = __builtin_amdgcn_mfma_f32_16x16x32_f16(ah, bl_, acc[nt], 0, 0, 0);
      acc[nt] = __builtin_amdgcn_mfma_f32_16x16x32_f16(al, bh_, acc[nt], 0, 0, 0);
    }
  }
#pragma unroll
  for (int nt = 0; nt < 2; ++nt) {
#pragma unroll
    for (int r = 0; r < 4; ++r) {
      const int si = m0 + quad * 4 + r;
      const size_t idx = ((size_t)(b_ * SS + si)) * EE + hh * HD + nh * 32 +
                         nt * 16 + l16;
      HL sp = split16(acc[nt][r]);
      oh[idx] = sp.h;
      ol[idx] = sp.l;
    }
  }
}

// ---------------------------------------------------------------------------
// K_out: LDS-staged 3-term f16 MFMA GEMM, fp32 output + bias.
// Same structure as k_qkv_mfma. grid (8 nb, 32 mb), block 256.
__global__ __launch_bounds__(256) void k_out_mfma(
    const _Float16* __restrict__ oh, const _Float16* __restrict__ ol,
    const _Float16* __restrict__ Wth, const _Float16* __restrict__ Wtl,
    const float* __restrict__ bo, float* __restrict__ out) {
  const int tid = threadIdx.x;
  const int wave = tid >> 6, lane = tid & 63;
  const int quad = lane >> 4, l16 = lane & 15;
  const int m0 = blockIdx.y * 64;
  const int n0 = blockIdx.x * 64;
  const _Float16* Bh = Wth + (size_t)3 * EE * EE;  // Wo^T
  const _Float16* Bl = Wtl + (size_t)3 * EE * EE;

  __shared__ _Float16 LAh[64][72], LAl[64][72], LBh[64][72], LBl[64][72];

  const int sr0 = tid >> 3, sc0 = (tid & 7) * 8;
  const int sr1 = (tid + 256) >> 3, sc1 = sc0;

  f32x4 acc[4] = {};
  for (int k0 = 0; k0 < EE; k0 += 64) {
    if (k0) __syncthreads();
    *(f16x8*)&LAh[sr0][sc0] = *(const f16x8*)(oh + (size_t)(m0 + sr0) * EE + k0 + sc0);
    *(f16x8*)&LAl[sr0][sc0] = *(const f16x8*)(ol + (size_t)(m0 + sr0) * EE + k0 + sc0);
    *(f16x8*)&LBh[sr0][sc0] = *(const f16x8*)(Bh + (size_t)(n0 + sr0) * EE + k0 + sc0);
    *(f16x8*)&LBl[sr0][sc0] = *(const f16x8*)(Bl + (size_t)(n0 + sr0) * EE + k0 + sc0);
    *(f16x8*)&LAh[sr1][sc1] = *(const f16x8*)(oh + (size_t)(m0 + sr1) * EE + k0 + sc1);
    *(f16x8*)&LAl[sr1][sc1] = *(const f16x8*)(ol + (size_t)(m0 + sr1) * EE + k0 + sc1);
    *(f16x8*)&LBh[sr1][sc1] = *(const f16x8*)(Bh + (size_t)(n0 + sr1) * EE + k0 + sc1);
    *(f16x8*)&LBl[sr1][sc1] = *(const f16x8*)(Bl + (size_t)(n0 + sr1) * EE + k0 + sc1);
    __syncthreads();
#pragma unroll
    for (int kk = 0; kk < 64; kk += 32) {
      f16x8 ah = *(const f16x8*)&LAh[wave * 16 + l16][kk + quad * 8];
      f16x8 al = *(const f16x8*)&LAl[wave * 16 + l16][kk + quad * 8];
#pragma unroll
      for (int nt = 0; nt < 4; ++nt) {
        f16x8 bhf = *(const f16x8*)&LBh[nt * 16 + l16][kk + quad * 8];
        f16x8 blf = *(const f16x8*)&LBl[nt * 16 + l16][kk + quad * 8];
        acc[nt] = __builtin_amdgcn_mfma_f32_16x16x32_f16(ah, bhf, acc[nt], 0, 0, 0);
        acc[nt] = __builtin_amdgcn_mfma_f32_16x16x32_f16(ah, blf, acc[nt], 0, 0, 0);
        acc[nt] = __builtin_amdgcn_mfma_f32_16x16x32_f16(al, bhf, acc[nt], 0, 0, 0);
      }
    }
  }
  const int mbase = m0 + wave * 16 + quad * 4;
#pragma unroll
  for (int nt = 0; nt < 4; ++nt) {
    const int col = n0 + nt * 16 + l16;
    const float bb = bo[col];
#pragma unroll
    for (int r = 0; r < 4; ++r) {
      const int m = mbase + r;
      out[(size_t)m * EE + col] = acc[nt][r] + bb;
    }
  }
}

// ---------------------------------------------------------------------------
extern "C" void kernel_launch(void* const* d_in, const int* in_sizes, int n_in,
                              void* d_out, int out_size, void* d_ws,
                              size_t ws_size, hipStream_t stream) {
  const float* x = (const float*)d_in[0];
  const float* Wq = (const float*)d_in[1];
  const float* bq = (const float*)d_in[2];
  const float* Wk = (const float*)d_in[3];
  const float* bk = (const float*)d_in[4];
  const float* Wv = (const float*)d_in[5];
  const float* bv = (const float*)d_in[6];
  const float* Wo = (const float*)d_in[7];
  const float* bo = (const float*)d_in[8];
  const float* w1 = (const float*)d_in[9];
  const float* b1 = (const float*)d_in[10];
  const float* w2 = (const float*)d_in[11];
  const float* b2 = (const float*)d_in[12];
  const float* tau = (const float*)d_in[13];
  float* out = (float*)d_out;

  const size_t NX = (size_t)2048 * EE;           // 1M elems (x, o)
  const size_t NW = (size_t)4 * EE * EE;         // 1M elems (4 W's)
  const size_t NQK = (size_t)BB * NH * SS * HD;  // 1M elems

  _Float16* xh = (_Float16*)d_ws;
  _Float16* xl = xh + NX;
  _Float16* Wth = xl + NX;
  _Float16* Wtl = Wth + NW;
  _Float16* qh = Wtl + NW;
  _Float16* ql = qh + NQK;
  _Float16* kh = ql + NQK;
  _Float16* kl = kh + NQK;
  float* v = (float*)(kl + NQK);
  _Float16* vth = (_Float16*)(v + NQK);
  _Float16* vtl = vth + NQK;
  float* s = (float*)(vtl + NQK);
  float* ma = s + (size_t)BB * NH * SS * SS;
  float* t_un = ma + (size_t)BB * SS * SS;
  float* T = t_un + (size_t)BB * SS * SS;
  float* rowred = T + 8192;
  float* cst = rowred + 2048 * 8;
  _Float16* oh = xh;  // alias: x dead after k_qkv_mfma
  _Float16* ol = xl;

  k_prep<<<785, 256, 0, stream>>>(w1, b1, w2, b2, T, x, xh, xl, Wq, Wk, Wv, Wo,
                                  Wth, Wtl);
  k_qkv_mfma<<<dim3(8, 32, 3), 256, 0, stream>>>(xh, xl, Wth, Wtl, bq, bk, bv,
                                                 qh, ql, kh, kl, v);
  k_scores_mfma<<<dim3(8, 8, 32), 256, 0, stream>>>(qh, ql, kh, kl, s);
  k_vt<<<dim3(8, 32), 256, 0, stream>>>(v, vth, vtl);
  k_rowstat<<<2048, 64, 0, stream>>>(s, T, ma, t_un, rowred);
  k_consts<<<4, 256, 0, stream>>>(rowred, cst);
  k_blend<<<16384, 64, 0, stream>>>(s, ma, t_un, cst, tau);
  k_av_mfma<<<dim3(2, 8, 32), 256, 0, stream>>>(s, vth, vtl, oh, ol);
  k_out_mfma<<<dim3(8, 32), 256, 0, stream>>>(oh, ol, Wth, Wtl, bo, out);
}